// Round 1
// baseline (483.248 us; speedup 1.0000x reference)
//
#include <hip/hip_runtime.h>
#include <stdint.h>

typedef unsigned long long ull;
typedef unsigned int uint;
typedef unsigned short ushort;

typedef __attribute__((ext_vector_type(8))) short short8;
typedef __attribute__((ext_vector_type(4))) float floatx4;

#define B   64
#define C   768
#define HW  576
#define K   50
#define NLOC (B*K)          // 3200

// ---- workspace layout (bytes) ----
#define OFF_SLOTS   0            // 64 floats
#define OFF_COLSUM  256          // 6*768*4 = 18432
#define OFF_NN1     18688        // 64*576*8 = 294912
#define OFF_NN2     313600       // 294912
#define OFF_SELP    608512       // 2*64*50*4 = 25600
#define OFF_SELQ    634112       // 25600
#define OFF_NORM    659712       // 2*64*576*4 = 294912
#define OFF_XT      954624       // 2*64*576*768*2 = 113246208  (dead after gather -> reused as Mp)
#define OFF_MP      OFF_XT       // 4 mats * 5 splits * 768*768*4 = 47185920 (fits in XT region)
#define OFF_XGT     114200832    // 4*768*3200*2 = 19660800
#define OFF_M       133861632    // 6*768*768*4 = 14155776
// total 148017408

#define SLOT_INVG 0
#define SLOT_STD  1   // +mat (0..5)
#define SLOT_COV  7   // +mat (0..5)
#define SLOT_INV1 13
#define SLOT_INV2 14

__device__ __forceinline__ ull umin64(ull a, ull b) { return a < b ? a : b; }

__device__ __forceinline__ float bf2f_lo(uint u) { return __uint_as_float(u << 16); }
__device__ __forceinline__ float bf2f_hi(uint u) { return __uint_as_float(u & 0xffff0000u); }
__device__ __forceinline__ float bf2f(ushort u) { return __uint_as_float(((uint)u) << 16); }

__device__ __forceinline__ ushort f2bf(float f) {
    uint u = __float_as_uint(f);
    uint r = (u + 0x7fffu + ((u >> 16) & 1u)) >> 16;   // RNE
    return (ushort)r;
}

__device__ __forceinline__ float blk_reduce_sum(float v, float* s4) {
    for (int off = 32; off > 0; off >>= 1) v += __shfl_down(v, off, 64);
    int lane = threadIdx.x & 63, w = threadIdx.x >> 6;
    if (lane == 0) s4[w] = v;
    __syncthreads();
    float r = 0.f;
    if (threadIdx.x == 0) r = s4[0] + s4[1] + s4[2] + s4[3];
    return r;
}

// ---------- convert fp32 [b][c][p] -> bf16 xT[which][b][p][c] + fused norms ----------
// v2: float4 loads held in registers (ILP), scalar LDS traffic <=2-way bank aliased,
//     uint4 (16B) stores of packed bf16, norm computed from rounded values in regs.
__global__ __launch_bounds__(256) void convert_kernel(const float* __restrict__ x1,
                                                      const float* __restrict__ x2,
                                                      ushort* __restrict__ xT,
                                                      float* __restrict__ norm) {
    int z = blockIdx.z;
    int which = z >> 6, b = z & 63;
    const float* X = which ? x2 : x1;
    int p0 = blockIdx.x * 64, c0 = blockIdx.y * 64;
    __shared__ float tile[64][65];   // [c][p], stride 65 -> scalar access 2-way max

    int t = threadIdx.x;
    int f4 = t & 15;                 // float4 column within a c-row (p direction)
    int r0 = t >> 4;                 // 0..15

    // ---- load phase: 4 independent 16B loads per thread ----
    const float* src = X + ((size_t)b * C + c0) * HW + p0;
    float4 v[4];
#pragma unroll
    for (int i = 0; i < 4; ++i) {
        int c = r0 + i * 16;
        v[i] = *(const float4*)(src + (size_t)c * HW + f4 * 4);
    }
#pragma unroll
    for (int i = 0; i < 4; ++i) {
        int c = r0 + i * 16;
        tile[c][f4 * 4 + 0] = v[i].x;
        tile[c][f4 * 4 + 1] = v[i].y;
        tile[c][f4 * 4 + 2] = v[i].z;
        tile[c][f4 * 4 + 3] = v[i].w;
    }
    __syncthreads();

    // ---- store phase: each thread emits two 16B chunks (8 bf16 along c at fixed p) ----
    ushort* dstbase = xT + (((size_t)which * B + b) * HW + p0) * C + c0;
    float* nrm = norm + ((size_t)which * B + b) * HW + p0;
#pragma unroll
    for (int half = 0; half < 2; ++half) {
        int chunk = t + half * 256;       // 0..511
        int p = chunk >> 3;               // 0..63
        int j = chunk & 7;                // c-chunk of 8
        float ss = 0.f;
        uint pk[4];
#pragma unroll
        for (int i = 0; i < 4; ++i) {
            float a  = tile[8 * j + 2 * i][p];
            float bb = tile[8 * j + 2 * i + 1][p];
            ushort ba = f2bf(a), bc = f2bf(bb);
            pk[i] = (uint)ba | ((uint)bc << 16);
            float ra = bf2f(ba), rb = bf2f(bc);
            ss = fmaf(ra, ra, ss);
            ss = fmaf(rb, rb, ss);
        }
        *(uint4*)(dstbase + (size_t)p * C + 8 * j) = *(const uint4*)pk;
        // reduce sum-of-squares across the 8 lanes sharing p
        ss += __shfl_xor(ss, 4, 8);
        ss += __shfl_xor(ss, 2, 8);
        ss += __shfl_xor(ss, 1, 8);
        if (j == 0) atomicAdd(&nrm[p], ss);
    }
}

// ---------- cdist Gram via MFMA, 128x128 tile, XCD-swizzled 1-D grid ----------
__global__ __launch_bounds__(256) void cdist_mfma(const ushort* __restrict__ xT,
                                                  const float* __restrict__ norm,
                                                  ull* __restrict__ nn1,
                                                  ull* __restrict__ nn2) {
    int id = blockIdx.x;
    int xcd = id & 7, slot = id >> 3;
    int b = xcd + 8 * (slot / 25);      // all 25 tiles of a batch share one XCD slot
    int t = slot % 25;
    int qt = t % 5, pt = t / 5;

    const ushort* X1 = xT + (size_t)b * HW * C;
    const ushort* X2 = xT + (size_t)(B + b) * HW * C;

    __shared__ ull pool[4224];          // 33792 B: A(16384)+B(16384); red overlays
    char* As = (char*)pool;
    char* Bs = As + 16384;

    int tid = threadIdx.x;
    int w = tid >> 6, l = tid & 63;
    int quad = l >> 4, col = l & 15;
    int lrow = l >> 2, pos = l & 3;

    const ushort* gA[2][2]; const ushort* gB[2][2];
    char* dA[2][2]; char* dB[2][2];
#pragma unroll
    for (int n = 0; n < 2; ++n) {
        int sm = w * 32 + n * 16 + lrow;            // LDS row 0..127
        int cdat = pos ^ ((sm >> 1) & 3);
        int p = pt * 128 + sm; if (p >= HW) p = HW - 1;
        int q = qt * 128 + sm; if (q >= HW) q = HW - 1;
#pragma unroll
        for (int s = 0; s < 2; ++s) {
            gA[s][n] = X1 + (size_t)p * C + s * 32 + cdat * 8;
            gB[s][n] = X2 + (size_t)q * C + s * 32 + cdat * 8;
            dA[s][n] = As + s * 8192 + w * 2048 + n * 1024;
            dB[s][n] = Bs + s * 8192 + w * 2048 + n * 1024;
        }
    }

    int offA[4], offB[4];
#pragma unroll
    for (int i = 0; i < 4; ++i) {
        int m_loc = (w >> 1) * 64 + i * 16 + col;
        offA[i] = m_loc * 64 + ((quad ^ ((m_loc >> 1) & 3)) * 16);
        int n_loc = (w & 1) * 64 + i * 16 + col;
        offB[i] = n_loc * 64 + ((quad ^ ((n_loc >> 1) & 3)) * 16);
    }

    floatx4 zero = {0.f, 0.f, 0.f, 0.f};
    floatx4 acc[4][4];
#pragma unroll
    for (int i = 0; i < 4; ++i)
#pragma unroll
        for (int j = 0; j < 4; ++j) acc[i][j] = zero;

    for (int k0 = 0; k0 < C; k0 += 64) {
        __syncthreads();
#pragma unroll
        for (int s = 0; s < 2; ++s)
#pragma unroll
            for (int n = 0; n < 2; ++n) {
                __builtin_amdgcn_global_load_lds(
                    (const __attribute__((address_space(1))) void*)(gA[s][n] + k0),
                    (__attribute__((address_space(3))) void*)dA[s][n], 16, 0, 0);
                __builtin_amdgcn_global_load_lds(
                    (const __attribute__((address_space(1))) void*)(gB[s][n] + k0),
                    (__attribute__((address_space(3))) void*)dB[s][n], 16, 0, 0);
            }
        __syncthreads();
#pragma unroll
        for (int s = 0; s < 2; ++s) {
            short8 a[4], bb[4];
#pragma unroll
            for (int i = 0; i < 4; ++i) a[i] = *(const short8*)(As + s * 8192 + offA[i]);
#pragma unroll
            for (int j = 0; j < 4; ++j) bb[j] = *(const short8*)(Bs + s * 8192 + offB[j]);
#pragma unroll
            for (int i = 0; i < 4; ++i)
#pragma unroll
                for (int j = 0; j < 4; ++j)
                    acc[i][j] = __builtin_amdgcn_mfma_f32_16x16x32_bf16(a[i], bb[j], acc[i][j], 0, 0, 0);
        }
    }

    const float* n1g = norm + (size_t)b * HW;
    const float* n2g = norm + (size_t)(B + b) * HW;
    float n1v[4][4]; bool vp[4][4];
    float n2v[4];    bool vq[4];
#pragma unroll
    for (int i = 0; i < 4; ++i)
#pragma unroll
        for (int r = 0; r < 4; ++r) {
            int p = pt * 128 + (w >> 1) * 64 + i * 16 + quad * 4 + r;
            vp[i][r] = (p < HW);
            n1v[i][r] = n1g[p < HW ? p : (HW - 1)];
        }
#pragma unroll
    for (int j = 0; j < 4; ++j) {
        int q = qt * 128 + (w & 1) * 64 + j * 16 + col;
        vq[j] = (q < HW);
        n2v[j] = n2g[q < HW ? q : (HW - 1)];
    }

    __syncthreads();
    typedef ull row33[33];
    row33* red = (row33*)pool;

    // pass 1: per-p min over q
#pragma unroll
    for (int i = 0; i < 4; ++i)
#pragma unroll
        for (int r = 0; r < 4; ++r) {
            int p_loc = (w >> 1) * 64 + i * 16 + quad * 4 + r;
            ull best = ~0ull;
#pragma unroll
            for (int j = 0; j < 4; ++j) {
                if (!vq[j]) continue;
                float d2 = fmaxf(n1v[i][r] + n2v[j] - 2.0f * acc[i][j][r], 0.0f);
                unsigned q_glob = qt * 128 + (w & 1) * 64 + j * 16 + col;
                best = umin64(best, ((ull)__float_as_uint(d2) << 32) | q_glob);
            }
            red[p_loc][(w & 1) * 16 + col] = best;
        }
    __syncthreads();
    if (tid < 128) {
        int p_glob = pt * 128 + tid;
        ull m = ~0ull;
#pragma unroll
        for (int x = 0; x < 32; ++x) m = umin64(m, red[tid][x]);
        if (p_glob < HW) atomicMin(&nn1[(size_t)b * HW + p_glob], m);
    }
    __syncthreads();
    // pass 2: per-q min over p
#pragma unroll
    for (int j = 0; j < 4; ++j) {
        int q_loc = (w & 1) * 64 + j * 16 + col;
        ull best = ~0ull;
#pragma unroll
        for (int i = 0; i < 4; ++i)
#pragma unroll
            for (int r = 0; r < 4; ++r) {
                if (!vp[i][r]) continue;
                float d2 = fmaxf(n1v[i][r] + n2v[j] - 2.0f * acc[i][j][r], 0.0f);
                unsigned p_glob = pt * 128 + (w >> 1) * 64 + i * 16 + quad * 4 + r;
                best = umin64(best, ((ull)__float_as_uint(d2) << 32) | p_glob);
            }
        red[q_loc][(w >> 1) * 4 + quad] = best;
    }
    __syncthreads();
    if (tid < 128) {
        int q_glob = qt * 128 + tid;
        ull m = ~0ull;
#pragma unroll
        for (int x = 0; x < 8; ++x) m = umin64(m, red[tid][x]);
        if (q_glob < HW) atomicMin(&nn2[(size_t)b * HW + q_glob], m);
    }
}

// ---------- top-k: one wave per (b,dir), keys in registers ----------
__global__ __launch_bounds__(64) void select_topk_wave(const ull* __restrict__ nn1,
                                                       const ull* __restrict__ nn2,
                                                       int* __restrict__ sel_p,
                                                       int* __restrict__ sel_q) {
    int b = blockIdx.x, dir = blockIdx.y;
    const ull* nn = dir ? nn2 : nn1;
    int lane = threadIdx.x;
    ull key[9]; uint qv[9];
#pragma unroll
    for (int r = 0; r < 9; ++r) {
        int p = r * 64 + lane;
        ull e = nn[(size_t)b * HW + p];
        key[r] = (e & 0xFFFFFFFF00000000ull) | (unsigned)p;
        qv[r] = (uint)(e & 0xFFFFFFFFu);
    }
    int* sp = sel_p + (dir * B + b) * K;
    int* sq = sel_q + (dir * B + b) * K;
    for (int it = 0; it < K; ++it) {
        ull m = key[0];
#pragma unroll
        for (int r = 1; r < 9; ++r) m = umin64(m, key[r]);
#pragma unroll
        for (int off = 32; off > 0; off >>= 1) m = umin64(m, __shfl_xor(m, off, 64));
#pragma unroll
        for (int r = 0; r < 9; ++r) {
            if (key[r] == m) {
                sp[it] = (int)(uint)(m & 0xFFFFFFFFu);
                sq[it] = (int)qv[r];
                key[r] = ~0ull;
            }
        }
    }
}

// ---------- gather into XgT[s][c][i], i = j*64 + b (coalesced writes) ----------
// s: 0=x1[sel_p d0] 1=x2[sel_q d0] 2=x2[sel_p d1] 3=x1[sel_q d1]
__global__ __launch_bounds__(256) void gather_jmajor(const ushort* __restrict__ xT,
                                                     const int* __restrict__ sel_p,
                                                     const int* __restrict__ sel_q,
                                                     ushort* __restrict__ XgT) {
    int j = blockIdx.x, s = blockIdx.y;
    int dir = s >> 1;
    int whichsrc = (s == 1 || s == 2) ? 1 : 0;
    const int* sel = (s & 1) ? sel_q : sel_p;
    __shared__ int sidx[64];
    __shared__ uint buf[64][33];
    int tid = threadIdx.x;
    if (tid < 64) sidx[tid] = sel[(dir * B + tid) * K + j];
    __syncthreads();
    int rb = tid >> 2, u = tid & 3;     // read mapping: row rb, quarter u
    const ushort* srow = xT + (((size_t)whichsrc * B + rb) * HW + sidx[rb]) * C;
    int wv = tid >> 6, lb = tid & 63;   // write mapping: lane = b
    ushort* obase = XgT + (size_t)s * C * NLOC + (size_t)j * 64 + lb;
    for (int ch = 0; ch < 12; ++ch) {
        __syncthreads();
        uint4 v0 = *(const uint4*)(srow + ch * 64 + u * 8);
        uint4 v1 = *(const uint4*)(srow + ch * 64 + (u + 4) * 8);
        buf[rb][u * 4 + 0] = v0.x; buf[rb][u * 4 + 1] = v0.y;
        buf[rb][u * 4 + 2] = v0.z; buf[rb][u * 4 + 3] = v0.w;
        buf[rb][(u + 4) * 4 + 0] = v1.x; buf[rb][(u + 4) * 4 + 1] = v1.y;
        buf[rb][(u + 4) * 4 + 2] = v1.z; buf[rb][(u + 4) * 4 + 3] = v1.w;
        __syncthreads();
#pragma unroll
        for (int st = 0; st < 16; ++st) {
            int cl = wv + st * 4;
            uint uv = buf[lb][cl >> 1];
            ushort val = (cl & 1) ? (ushort)(uv >> 16) : (ushort)(uv & 0xffffu);
            obase[(size_t)(ch * 64 + cl) * NLOC] = val;
        }
    }
}

// ---------- Mp[mat][split] = partial X^T X via MFMA, 128x128 tile, split-K=5 ----------
__global__ __launch_bounds__(256) void ata_mfma(const ushort* __restrict__ XgT,
                                                float* __restrict__ Mp) {
    int bx = blockIdx.x;                 // 0..35
    int mat = blockIdx.y, split = blockIdx.z;
    int rt = bx / 6, ct = bx % 6;
    const ushort* X = XgT + (size_t)mat * C * NLOC;

    __shared__ ull pool[4096];           // 32768 B
    char* As = (char*)pool;
    char* Bs = As + 16384;

    int tid = threadIdx.x;
    int w = tid >> 6, l = tid & 63;
    int quad = l >> 4, col = l & 15;
    int lrow = l >> 2, pos = l & 3;

    const ushort* gA[2][2]; const ushort* gB[2][2];
    char* dA[2][2]; char* dB[2][2];
#pragma unroll
    for (int n = 0; n < 2; ++n) {
        int sm = w * 32 + n * 16 + lrow;
        int cdat = pos ^ ((sm >> 1) & 3);
#pragma unroll
        for (int s = 0; s < 2; ++s) {
            gA[s][n] = X + (size_t)(rt * 128 + sm) * NLOC + split * 640 + s * 32 + cdat * 8;
            gB[s][n] = X + (size_t)(ct * 128 + sm) * NLOC + split * 640 + s * 32 + cdat * 8;
            dA[s][n] = As + s * 8192 + w * 2048 + n * 1024;
            dB[s][n] = Bs + s * 8192 + w * 2048 + n * 1024;
        }
    }

    int offA[4], offB[4];
#pragma unroll
    for (int i = 0; i < 4; ++i) {
        int m_loc = (w >> 1) * 64 + i * 16 + col;
        offA[i] = m_loc * 64 + ((quad ^ ((m_loc >> 1) & 3)) * 16);
        int n_loc = (w & 1) * 64 + i * 16 + col;
        offB[i] = n_loc * 64 + ((quad ^ ((n_loc >> 1) & 3)) * 16);
    }

    floatx4 zero = {0.f, 0.f, 0.f, 0.f};
    floatx4 acc[4][4];
#pragma unroll
    for (int i = 0; i < 4; ++i)
#pragma unroll
        for (int j = 0; j < 4; ++j) acc[i][j] = zero;

    for (int k0 = 0; k0 < 640; k0 += 64) {
        __syncthreads();
#pragma unroll
        for (int s = 0; s < 2; ++s)
#pragma unroll
            for (int n = 0; n < 2; ++n) {
                __builtin_amdgcn_global_load_lds(
                    (const __attribute__((address_space(1))) void*)(gA[s][n] + k0),
                    (__attribute__((address_space(3))) void*)dA[s][n], 16, 0, 0);
                __builtin_amdgcn_global_load_lds(
                    (const __attribute__((address_space(1))) void*)(gB[s][n] + k0),
                    (__attribute__((address_space(3))) void*)dB[s][n], 16, 0, 0);
            }
        __syncthreads();
#pragma unroll
        for (int s = 0; s < 2; ++s) {
            short8 a[4], bb[4];
#pragma unroll
            for (int i = 0; i < 4; ++i) a[i] = *(const short8*)(As + s * 8192 + offA[i]);
#pragma unroll
            for (int j = 0; j < 4; ++j) bb[j] = *(const short8*)(Bs + s * 8192 + offB[j]);
#pragma unroll
            for (int i = 0; i < 4; ++i)
#pragma unroll
                for (int j = 0; j < 4; ++j)
                    acc[i][j] = __builtin_amdgcn_mfma_f32_16x16x32_bf16(a[i], bb[j], acc[i][j], 0, 0, 0);
        }
    }

    float* Mo = Mp + (size_t)(mat * 5 + split) * C * C;
#pragma unroll
    for (int i = 0; i < 4; ++i)
#pragma unroll
        for (int j = 0; j < 4; ++j)
#pragma unroll
            for (int r = 0; r < 4; ++r) {
                int row = rt * 128 + (w >> 1) * 64 + i * 16 + quad * 4 + r;
                int cc  = ct * 128 + (w & 1) * 64 + j * 16 + col;
                Mo[(size_t)row * C + cc] = acc[i][j][r];
            }
}

// ---------- reduce Mp splits -> M (mats 0..3) ----------
__global__ __launch_bounds__(256) void reduce_mp(const float* __restrict__ Mp,
                                                 float* __restrict__ M) {
    int mat = blockIdx.y;
    int i = blockIdx.x * 256 + threadIdx.x;            // float4 index, 0..147455
    float4 r = {0.f, 0.f, 0.f, 0.f};
#pragma unroll
    for (int s = 0; s < 5; ++s) {
        const float4* a = (const float4*)(Mp + (size_t)(mat * 5 + s) * C * C);
        float4 v = a[i];
        r.x += v.x; r.y += v.y; r.z += v.z; r.w += v.w;
    }
    ((float4*)(M + (size_t)mat * C * C))[i] = r;
}

// ---------- fp32 X^T X for pooled mats (4,5), n=64 ----------
__global__ __launch_bounds__(256) void ata_pooled(const float* __restrict__ p1,
                                                  const float* __restrict__ p2,
                                                  float* __restrict__ M) {
    int mat = 4 + blockIdx.z;
    const float* X = (mat == 4) ? p1 : p2;
    int n = B;
    float* Mo = M + (size_t)mat * C * C;
    int ct = blockIdx.x, rt = blockIdx.y;

    __shared__ float As[16][64];
    __shared__ float Bs[16][64];
    int tid = threadIdx.x;
    int tx = tid & 15, ty = tid >> 4;
    int lr = tid >> 4, lc = (tid & 15) * 4;

    float acc[4][4] = {};
    for (int k0 = 0; k0 < n; k0 += 16) {
        float4 av = *(const float4*)&X[(size_t)(k0 + lr) * C + rt * 64 + lc];
        float4 bv = *(const float4*)&X[(size_t)(k0 + lr) * C + ct * 64 + lc];
        __syncthreads();
        *(float4*)&As[lr][lc] = av;
        *(float4*)&Bs[lr][lc] = bv;
        __syncthreads();
#pragma unroll
        for (int kk = 0; kk < 16; ++kk) {
            float4 af = *(const float4*)&As[kk][ty * 4];
            float4 bf = *(const float4*)&Bs[kk][tx * 4];
            float a[4] = {af.x, af.y, af.z, af.w};
            float bb[4] = {bf.x, bf.y, bf.z, bf.w};
#pragma unroll
            for (int i = 0; i < 4; ++i)
#pragma unroll
                for (int j = 0; j < 4; ++j)
                    acc[i][j] = fmaf(a[i], bb[j], acc[i][j]);
        }
    }
#pragma unroll
    for (int i = 0; i < 4; ++i) {
        float4 o = {acc[i][0], acc[i][1], acc[i][2], acc[i][3]};
        *(float4*)&Mo[(size_t)(rt * 64 + ty * 4 + i) * C + ct * 64 + tx * 4] = o;
    }
}

// ---------- colsum for mats 0..3 from XgT (no atomics) ----------
__global__ __launch_bounds__(256) void colsum4_kernel(const ushort* __restrict__ XgT,
                                                      float* __restrict__ colsum) {
    int mat = blockIdx.y, cb = blockIdx.x * 4;
    int r = threadIdx.x >> 6, lane = threadIdx.x & 63;
    const ushort* row = XgT + ((size_t)mat * C + cb + r) * NLOC;
    float s = 0.f;
    for (int i = lane; i < NLOC; i += 64) s += bf2f(row[i]);
    for (int off = 32; off > 0; off >>= 1) s += __shfl_down(s, off, 64);
    if (lane == 0) colsum[mat * C + cb + r] = s;
}

// ---------- colsum pooled (no atomics) ----------
__global__ __launch_bounds__(256) void colsum_pooled(const float* __restrict__ p1,
                                                     const float* __restrict__ p2,
                                                     float* __restrict__ colsum) {
    int mat = 4 + blockIdx.y;
    const float* X = (mat == 4) ? p1 : p2;
    int c = blockIdx.x * 256 + threadIdx.x;
    float s = 0.f;
    for (int r = 0; r < B; ++r) s += X[(size_t)r * C + c];
    colsum[mat * C + c] = s;
}

// ---------- std term ----------
__global__ __launch_bounds__(256) void std_kernel(const float* __restrict__ M,
                                                  const float* __restrict__ colsum,
                                                  float* __restrict__ slots) {
    int mat = blockIdx.y;
    float n = (mat < 4) ? (float)NLOC : (float)B;
    int c = blockIdx.x * 256 + threadIdx.x;
    float r = 0.f;
    if (c < C) {
        float mcc = M[(size_t)mat * C * C + (size_t)c * C + c];
        float cs = colsum[mat * C + c];
        float var = (mcc - cs * cs / n) / (n - 1.0f);
        float sd = sqrtf(var + 1e-5f);
        float g = 1.0f - sd;
        r = g > 0.f ? g : 0.f;
    }
    __shared__ float s4[4];
    float t = blk_reduce_sum(r, s4);
    if (threadIdx.x == 0) atomicAdd(&slots[SLOT_STD + mat], t);
}

// ---------- cov term: 48 blocks x 16 rows per mat ----------
__global__ __launch_bounds__(256) void cov_kernel(const float* __restrict__ M,
                                                  const float* __restrict__ colsum,
                                                  float* __restrict__ slots) {
    int mat = blockIdx.y;
    float n = (mat < 4) ? (float)NLOC : (float)B;
    float invn1 = 1.0f / (n - 1.0f);
    const float* Mm = M + (size_t)mat * C * C;
    __shared__ float cs_s[C];
    for (int c = threadIdx.x; c < C; c += 256) cs_s[c] = colsum[mat * C + c];
    __syncthreads();
    float s = 0.f;
    int r0 = blockIdx.x * 16;
    for (int r = 0; r < 16; ++r) {
        int row = r0 + r;
        float csr = cs_s[row] / n;
        const float* Mr = Mm + (size_t)row * C;
        for (int c = threadIdx.x; c < C; c += 256) {
            float cv = (Mr[c] - csr * cs_s[c]) * invn1;
            if (c != row) s = fmaf(cv, cv, s);
        }
    }
    __shared__ float s4[4];
    float t = blk_reduce_sum(s, s4);
    if (threadIdx.x == 0) atomicAdd(&slots[SLOT_COV + mat], t);
}

// ---------- invariance terms ----------
__global__ __launch_bounds__(256) void inv_global_kernel(const float* __restrict__ p1,
                                                         const float* __restrict__ p2,
                                                         float* __restrict__ slots) {
    int idx = blockIdx.x * 256 + threadIdx.x;
    int stride = gridDim.x * 256;
    float s = 0.f;
    for (int i = idx; i < B * C; i += stride) {
        float d = p1[i] - p2[i];
        s = fmaf(d, d, s);
    }
    __shared__ float s4[4];
    float t = blk_reduce_sum(s, s4);
    if (threadIdx.x == 0) atomicAdd(&slots[SLOT_INVG], t);
}

__global__ __launch_bounds__(256) void inv_local2(const ushort* __restrict__ XgT,
                                                  float* __restrict__ slots) {
    int pair = blockIdx.y;
    const uint* A4 = (const uint*)(XgT + (size_t)(2 * pair) * C * NLOC);
    const uint* B4 = (const uint*)(XgT + (size_t)(2 * pair + 1) * C * NLOC);
    int idx = blockIdx.x * 256 + threadIdx.x;
    int stride = gridDim.x * 256;
    int n = C * NLOC / 2;
    float s = 0.f;
    for (int i = idx; i < n; i += stride) {
        uint ua = A4[i], ub = B4[i];
        float d0 = bf2f_lo(ua) - bf2f_lo(ub);
        float d1 = bf2f_hi(ua) - bf2f_hi(ub);
        s = fmaf(d0, d0, s);
        s = fmaf(d1, d1, s);
    }
    __shared__ float s4[4];
    float t = blk_reduce_sum(s, s4);
    if (threadIdx.x == 0) atomicAdd(&slots[(pair == 0) ? SLOT_INV1 : SLOT_INV2], t);
}

// ---------- final combine ----------
__global__ void final_kernel(const float* __restrict__ slots, float* __restrict__ out) {
    float std_t[6], cov_t[6];
    for (int m = 0; m < 6; ++m) {
        std_t[m] = slots[SLOT_STD + m] / (float)C * 0.5f;
        cov_t[m] = slots[SLOT_COV + m] / (float)C;
    }
    float inv_g = slots[SLOT_INVG] / (float)(B * C);
    float global_loss = 25.0f * inv_g + 25.0f * (std_t[4] + std_t[5]) + (cov_t[4] + cov_t[5]);
    float inv1 = 25.0f * slots[SLOT_INV1] / (float)(NLOC * C);
    float inv2 = 25.0f * slots[SLOT_INV2] / (float)(NLOC * C);
    float var1 = 25.0f * (std_t[0] + std_t[1]);
    float var2 = 25.0f * (std_t[2] + std_t[3]);
    float cov1 = cov_t[0] + cov_t[1];
    float cov2 = cov_t[2] + cov_t[3];
    float local_loss = (inv1 + inv2) * 0.5f + (var1 + var2) * 0.5f + (cov1 + cov2) * 0.5f;
    out[0] = 0.5f * global_loss + 0.5f * local_loss;
}

extern "C" void kernel_launch(void* const* d_in, const int* in_sizes, int n_in,
                              void* d_out, int out_size, void* d_ws, size_t ws_size,
                              hipStream_t stream) {
    const float* spatial_1 = (const float*)d_in[0];
    const float* pooled_1  = (const float*)d_in[1];
    const float* spatial_2 = (const float*)d_in[2];
    const float* pooled_2  = (const float*)d_in[3];
    float* out = (float*)d_out;

    char* ws = (char*)d_ws;
    float*  slots  = (float*)(ws + OFF_SLOTS);
    float*  colsum = (float*)(ws + OFF_COLSUM);
    ull*    nn1    = (ull*)(ws + OFF_NN1);
    ull*    nn2    = (ull*)(ws + OFF_NN2);
    int*    sel_p  = (int*)(ws + OFF_SELP);
    int*    sel_q  = (int*)(ws + OFF_SELQ);
    float*  norm   = (float*)(ws + OFF_NORM);
    ushort* xT     = (ushort*)(ws + OFF_XT);
    float*  Mp     = (float*)(ws + OFF_MP);   // overlays xT (dead after gather)
    ushort* XgT    = (ushort*)(ws + OFF_XGT);
    float*  M      = (float*)(ws + OFF_M);

    hipMemsetAsync(ws, 0, OFF_NN1, stream);                          // slots + colsum
    hipMemsetAsync(ws + OFF_NN1, 0xFF, OFF_SELP - OFF_NN1, stream);  // nn keys
    hipMemsetAsync(ws + OFF_NORM, 0, 294912, stream);                // norms (atomic accum)

    convert_kernel<<<dim3(9, 12, 128), 256, 0, stream>>>(spatial_1, spatial_2, xT, norm);
    cdist_mfma<<<1600, 256, 0, stream>>>(xT, norm, nn1, nn2);
    select_topk_wave<<<dim3(B, 2), 64, 0, stream>>>(nn1, nn2, sel_p, sel_q);
    gather_jmajor<<<dim3(K, 4), 256, 0, stream>>>(xT, sel_p, sel_q, XgT);
    ata_mfma<<<dim3(36, 4, 5), 256, 0, stream>>>(XgT, Mp);
    ata_pooled<<<dim3(12, 12, 2), 256, 0, stream>>>(pooled_1, pooled_2, M);
    reduce_mp<<<dim3(576, 4), 256, 0, stream>>>(Mp, M);
    colsum4_kernel<<<dim3(192, 4), 256, 0, stream>>>(XgT, colsum);
    colsum_pooled<<<dim3(3, 2), 256, 0, stream>>>(pooled_1, pooled_2, colsum);
    std_kernel<<<dim3(3, 6), 256, 0, stream>>>(M, colsum, slots);
    cov_kernel<<<dim3(48, 6), 256, 0, stream>>>(M, colsum, slots);
    inv_global_kernel<<<dim3(96), 256, 0, stream>>>(pooled_1, pooled_2, slots);
    inv_local2<<<dim3(300, 2), 256, 0, stream>>>(XgT, slots);
    final_kernel<<<1, 1, 0, stream>>>(slots, out);
}

// Round 2
// 479.860 us; speedup vs baseline: 1.0071x; 1.0071x over previous
//
#include <hip/hip_runtime.h>
#include <stdint.h>

typedef unsigned long long ull;
typedef unsigned int uint;
typedef unsigned short ushort;

typedef __attribute__((ext_vector_type(8))) short short8;
typedef __attribute__((ext_vector_type(4))) float floatx4;

#define B   64
#define C   768
#define HW  576
#define K   50
#define NLOC (B*K)          // 3200

// ---- workspace layout (bytes) ----
#define OFF_SLOTS   0            // 64 floats
#define OFF_COLSUM  256          // 6*768*4 = 18432
#define OFF_NN1     18688        // 64*576*8 = 294912
#define OFF_NN2     313600       // 294912
#define OFF_SELP    608512       // 2*64*50*4 = 25600
#define OFF_SELQ    634112       // 25600
#define OFF_NORM    659712       // 2*64*576*4 = 294912
#define OFF_XT      954624       // 2*64*576*768*2 = 113246208  (dead after gather -> reused as Mp)
#define OFF_MP      OFF_XT       // 4 mats * 5 splits * 768*768*4 = 47185920 (fits in XT region)
#define OFF_XGT     114200832    // 4*768*3200*2 = 19660800
#define OFF_M       133861632    // 6*768*768*4 = 14155776
// total 148017408

#define SLOT_INVG 0
#define SLOT_STD  1   // +mat (0..5)
#define SLOT_COV  7   // +mat (0..5)
#define SLOT_INV1 13
#define SLOT_INV2 14

__device__ __forceinline__ ull umin64(ull a, ull b) { return a < b ? a : b; }

__device__ __forceinline__ float bf2f_lo(uint u) { return __uint_as_float(u << 16); }
__device__ __forceinline__ float bf2f_hi(uint u) { return __uint_as_float(u & 0xffff0000u); }
__device__ __forceinline__ float bf2f(ushort u) { return __uint_as_float(((uint)u) << 16); }

__device__ __forceinline__ ushort f2bf(float f) {
    uint u = __float_as_uint(f);
    uint r = (u + 0x7fffu + ((u >> 16) & 1u)) >> 16;   // RNE
    return (ushort)r;
}

__device__ __forceinline__ float blk_reduce_sum(float v, float* s4) {
    for (int off = 32; off > 0; off >>= 1) v += __shfl_down(v, off, 64);
    int lane = threadIdx.x & 63, w = threadIdx.x >> 6;
    if (lane == 0) s4[w] = v;
    __syncthreads();
    float r = 0.f;
    if (threadIdx.x == 0) r = s4[0] + s4[1] + s4[2] + s4[3];
    return r;
}

// ---------- convert fp32 [b][c][p] -> bf16 xT[which][b][p][c] + fused norms ----------
// v3: NO LDS. Per-thread 4c x 4p in-register transpose; 12 c-chunks software-pipelined
//     2-deep (4 float4 loads always in flight during pack/stores). Norms finished
//     in-block via 16-lane shfl reduce -> plain store (no atomics, no memset needed).
__global__ __launch_bounds__(256) void convert_kernel(const float* __restrict__ x1,
                                                      const float* __restrict__ x2,
                                                      ushort* __restrict__ xT,
                                                      float* __restrict__ norm) {
    int z = blockIdx.y;
    int which = z >> 6, b = z & 63;
    const float* X = (which ? x2 : x1) + (size_t)b * C * HW;
    int p0 = blockIdx.x * 64;
    int t = threadIdx.x;
    int cq = t & 15;            // c quad (16 per 64-c chunk)
    int pq = t >> 4;            // p quad (16 -> 64 p)
    const float* src = X + p0 + 4 * pq;
    ushort* dstb = xT + (((size_t)which * B + b) * HW + p0) * C;   // [p][c] row-major
    float ss[4] = {0.f, 0.f, 0.f, 0.f};

    floatx4 A[4], Bf[4];
#define LOADCH(dst, ch)                                                               \
    {                                                                                 \
        _Pragma("unroll") for (int i = 0; i < 4; ++i)                                 \
            dst[i] = *(const floatx4*)(src + (size_t)((ch) * 64 + 4 * cq + i) * HW);  \
    }
#define STORECH(sv, ch)                                                               \
    {                                                                                 \
        _Pragma("unroll") for (int j = 0; j < 4; ++j) {                               \
            ushort u0 = f2bf(sv[0][j]), u1 = f2bf(sv[1][j]);                          \
            ushort u2 = f2bf(sv[2][j]), u3 = f2bf(sv[3][j]);                          \
            uint2 wv;                                                                 \
            wv.x = (uint)u0 | ((uint)u1 << 16);                                       \
            wv.y = (uint)u2 | ((uint)u3 << 16);                                       \
            *(uint2*)(dstb + (size_t)(4 * pq + j) * C + (ch) * 64 + 4 * cq) = wv;     \
            float r0 = bf2f(u0), r1 = bf2f(u1), r2 = bf2f(u2), r3 = bf2f(u3);         \
            ss[j] = fmaf(r0, r0, ss[j]); ss[j] = fmaf(r1, r1, ss[j]);                 \
            ss[j] = fmaf(r2, r2, ss[j]); ss[j] = fmaf(r3, r3, ss[j]);                 \
        }                                                                             \
    }

    LOADCH(A, 0);
    for (int ch = 0; ch < 12; ch += 2) {
        LOADCH(Bf, ch + 1);
        STORECH(A, ch);
        if (ch + 2 < 12) LOADCH(A, ch + 2);
        STORECH(Bf, ch + 1);
    }
#undef LOADCH
#undef STORECH
    // reduce ss[j] across the 16 lanes sharing pq (consecutive lanes)
#pragma unroll
    for (int j = 0; j < 4; ++j) {
        ss[j] += __shfl_xor(ss[j], 8, 16);
        ss[j] += __shfl_xor(ss[j], 4, 16);
        ss[j] += __shfl_xor(ss[j], 2, 16);
        ss[j] += __shfl_xor(ss[j], 1, 16);
    }
    float outv = (cq == 1) ? ss[1] : (cq == 2) ? ss[2] : (cq == 3) ? ss[3] : ss[0];
    if (cq < 4)
        norm[((size_t)which * B + b) * HW + p0 + 4 * pq + cq] = outv;
}

// ---------- shared ping-pong MFMA K-loop (T3/T4 minimum: counted vmcnt + raw barriers) ----------
// Two 64-col s-halves alternate: while computing half s, half s^1's loads are in flight.
// Each wave waits ONLY its own 4 outstanding loads (vmcnt(4)) before each joint barrier;
// overwrite of a half is issued only after the barrier that ends its read phase.
template<int NK>
__device__ __forceinline__ void gemm_pp(const ushort* (&gA)[2][2], const ushort* (&gB)[2][2],
                                        char* (&dA)[2][2], char* (&dB)[2][2],
                                        const char* As, const char* Bs,
                                        const int (&offA)[4], const int (&offB)[4],
                                        floatx4 (&acc)[4][4]) {
    auto issue = [&](int s, int k0) {
#pragma unroll
        for (int n = 0; n < 2; ++n) {
            __builtin_amdgcn_global_load_lds(
                (const __attribute__((address_space(1))) void*)(gA[s][n] + k0),
                (__attribute__((address_space(3))) void*)dA[s][n], 16, 0, 0);
            __builtin_amdgcn_global_load_lds(
                (const __attribute__((address_space(1))) void*)(gB[s][n] + k0),
                (__attribute__((address_space(3))) void*)dB[s][n], 16, 0, 0);
        }
    };
    auto compute = [&](int s) {
        short8 a[4], bb[4];
#pragma unroll
        for (int i = 0; i < 4; ++i) a[i] = *(const short8*)(As + s * 8192 + offA[i]);
#pragma unroll
        for (int j = 0; j < 4; ++j) bb[j] = *(const short8*)(Bs + s * 8192 + offB[j]);
#pragma unroll
        for (int i = 0; i < 4; ++i)
#pragma unroll
            for (int j = 0; j < 4; ++j)
                acc[i][j] = __builtin_amdgcn_mfma_f32_16x16x32_bf16(a[i], bb[j], acc[i][j], 0, 0, 0);
    };

    issue(0, 0);
    issue(1, 0);
    for (int k = 0; k < NK; ++k) {
        asm volatile("s_waitcnt vmcnt(4)" ::: "memory");   // own s0(k) loads done
        __builtin_amdgcn_s_barrier();
        __builtin_amdgcn_sched_barrier(0);
        compute(0);
        __builtin_amdgcn_sched_barrier(0);
        __builtin_amdgcn_s_barrier();                      // all waves done reading s0
        if (k + 1 < NK) {
            issue(0, (k + 1) * 64);
            asm volatile("s_waitcnt vmcnt(4)" ::: "memory");  // own s1(k) loads done
        } else {
            asm volatile("s_waitcnt vmcnt(0)" ::: "memory");  // tail: drain s1(NK-1)
        }
        __builtin_amdgcn_s_barrier();
        __builtin_amdgcn_sched_barrier(0);
        compute(1);
        __builtin_amdgcn_sched_barrier(0);
        __builtin_amdgcn_s_barrier();                      // all waves done reading s1
        if (k + 1 < NK) issue(1, (k + 1) * 64);
    }
    // loop exit: vmcnt == 0, all waves past final barrier
}

// ---------- cdist Gram via MFMA, 128x128 tile, XCD-swizzled 1-D grid ----------
__global__ __launch_bounds__(256) void cdist_mfma(const ushort* __restrict__ xT,
                                                  const float* __restrict__ norm,
                                                  ull* __restrict__ nn1,
                                                  ull* __restrict__ nn2) {
    int id = blockIdx.x;
    int xcd = id & 7, slot = id >> 3;
    int b = xcd + 8 * (slot / 25);      // all 25 tiles of a batch share one XCD slot
    int t = slot % 25;
    int qt = t % 5, pt = t / 5;

    const ushort* X1 = xT + (size_t)b * HW * C;
    const ushort* X2 = xT + (size_t)(B + b) * HW * C;

    __shared__ ull pool[4224];          // 33792 B: A(16384)+B(16384); red overlays
    char* As = (char*)pool;
    char* Bs = As + 16384;

    int tid = threadIdx.x;
    int w = tid >> 6, l = tid & 63;
    int quad = l >> 4, col = l & 15;
    int lrow = l >> 2, pos = l & 3;

    const ushort* gA[2][2]; const ushort* gB[2][2];
    char* dA[2][2]; char* dB[2][2];
#pragma unroll
    for (int n = 0; n < 2; ++n) {
        int sm = w * 32 + n * 16 + lrow;            // LDS row 0..127
        int cdat = pos ^ ((sm >> 1) & 3);
        int p = pt * 128 + sm; if (p >= HW) p = HW - 1;
        int q = qt * 128 + sm; if (q >= HW) q = HW - 1;
#pragma unroll
        for (int s = 0; s < 2; ++s) {
            gA[s][n] = X1 + (size_t)p * C + s * 32 + cdat * 8;
            gB[s][n] = X2 + (size_t)q * C + s * 32 + cdat * 8;
            dA[s][n] = As + s * 8192 + w * 2048 + n * 1024;
            dB[s][n] = Bs + s * 8192 + w * 2048 + n * 1024;
        }
    }

    int offA[4], offB[4];
#pragma unroll
    for (int i = 0; i < 4; ++i) {
        int m_loc = (w >> 1) * 64 + i * 16 + col;
        offA[i] = m_loc * 64 + ((quad ^ ((m_loc >> 1) & 3)) * 16);
        int n_loc = (w & 1) * 64 + i * 16 + col;
        offB[i] = n_loc * 64 + ((quad ^ ((n_loc >> 1) & 3)) * 16);
    }

    floatx4 zero = {0.f, 0.f, 0.f, 0.f};
    floatx4 acc[4][4];
#pragma unroll
    for (int i = 0; i < 4; ++i)
#pragma unroll
        for (int j = 0; j < 4; ++j) acc[i][j] = zero;

    gemm_pp<12>(gA, gB, dA, dB, As, Bs, offA, offB, acc);

    const float* n1g = norm + (size_t)b * HW;
    const float* n2g = norm + (size_t)(B + b) * HW;
    float n1v[4][4]; bool vp[4][4];
    float n2v[4];    bool vq[4];
#pragma unroll
    for (int i = 0; i < 4; ++i)
#pragma unroll
        for (int r = 0; r < 4; ++r) {
            int p = pt * 128 + (w >> 1) * 64 + i * 16 + quad * 4 + r;
            vp[i][r] = (p < HW);
            n1v[i][r] = n1g[p < HW ? p : (HW - 1)];
        }
#pragma unroll
    for (int j = 0; j < 4; ++j) {
        int q = qt * 128 + (w & 1) * 64 + j * 16 + col;
        vq[j] = (q < HW);
        n2v[j] = n2g[q < HW ? q : (HW - 1)];
    }

    __syncthreads();
    typedef ull row33[33];
    row33* red = (row33*)pool;

    // pass 1: per-p min over q
#pragma unroll
    for (int i = 0; i < 4; ++i)
#pragma unroll
        for (int r = 0; r < 4; ++r) {
            int p_loc = (w >> 1) * 64 + i * 16 + quad * 4 + r;
            ull best = ~0ull;
#pragma unroll
            for (int j = 0; j < 4; ++j) {
                if (!vq[j]) continue;
                float d2 = fmaxf(n1v[i][r] + n2v[j] - 2.0f * acc[i][j][r], 0.0f);
                unsigned q_glob = qt * 128 + (w & 1) * 64 + j * 16 + col;
                best = umin64(best, ((ull)__float_as_uint(d2) << 32) | q_glob);
            }
            red[p_loc][(w & 1) * 16 + col] = best;
        }
    __syncthreads();
    if (tid < 128) {
        int p_glob = pt * 128 + tid;
        ull m = ~0ull;
#pragma unroll
        for (int x = 0; x < 32; ++x) m = umin64(m, red[tid][x]);
        if (p_glob < HW) atomicMin(&nn1[(size_t)b * HW + p_glob], m);
    }
    __syncthreads();
    // pass 2: per-q min over p
#pragma unroll
    for (int j = 0; j < 4; ++j) {
        int q_loc = (w & 1) * 64 + j * 16 + col;
        ull best = ~0ull;
#pragma unroll
        for (int i = 0; i < 4; ++i)
#pragma unroll
            for (int r = 0; r < 4; ++r) {
                if (!vp[i][r]) continue;
                float d2 = fmaxf(n1v[i][r] + n2v[j] - 2.0f * acc[i][j][r], 0.0f);
                unsigned p_glob = pt * 128 + (w >> 1) * 64 + i * 16 + quad * 4 + r;
                best = umin64(best, ((ull)__float_as_uint(d2) << 32) | p_glob);
            }
        red[q_loc][(w >> 1) * 4 + quad] = best;
    }
    __syncthreads();
    if (tid < 128) {
        int q_glob = qt * 128 + tid;
        ull m = ~0ull;
#pragma unroll
        for (int x = 0; x < 8; ++x) m = umin64(m, red[tid][x]);
        if (q_glob < HW) atomicMin(&nn2[(size_t)b * HW + q_glob], m);
    }
}

// ---------- top-k: one wave per (b,dir), keys in registers ----------
__global__ __launch_bounds__(64) void select_topk_wave(const ull* __restrict__ nn1,
                                                       const ull* __restrict__ nn2,
                                                       int* __restrict__ sel_p,
                                                       int* __restrict__ sel_q) {
    int b = blockIdx.x, dir = blockIdx.y;
    const ull* nn = dir ? nn2 : nn1;
    int lane = threadIdx.x;
    ull key[9]; uint qv[9];
#pragma unroll
    for (int r = 0; r < 9; ++r) {
        int p = r * 64 + lane;
        ull e = nn[(size_t)b * HW + p];
        key[r] = (e & 0xFFFFFFFF00000000ull) | (unsigned)p;
        qv[r] = (uint)(e & 0xFFFFFFFFu);
    }
    int* sp = sel_p + (dir * B + b) * K;
    int* sq = sel_q + (dir * B + b) * K;
    for (int it = 0; it < K; ++it) {
        ull m = key[0];
#pragma unroll
        for (int r = 1; r < 9; ++r) m = umin64(m, key[r]);
#pragma unroll
        for (int off = 32; off > 0; off >>= 1) m = umin64(m, __shfl_xor(m, off, 64));
#pragma unroll
        for (int r = 0; r < 9; ++r) {
            if (key[r] == m) {
                sp[it] = (int)(uint)(m & 0xFFFFFFFFu);
                sq[it] = (int)qv[r];
                key[r] = ~0ull;
            }
        }
    }
}

// ---------- gather into XgT[s][c][i], i = j*64 + b (coalesced writes) ----------
// s: 0=x1[sel_p d0] 1=x2[sel_q d0] 2=x2[sel_p d1] 3=x1[sel_q d1]
__global__ __launch_bounds__(256) void gather_jmajor(const ushort* __restrict__ xT,
                                                     const int* __restrict__ sel_p,
                                                     const int* __restrict__ sel_q,
                                                     ushort* __restrict__ XgT) {
    int j = blockIdx.x, s = blockIdx.y;
    int dir = s >> 1;
    int whichsrc = (s == 1 || s == 2) ? 1 : 0;
    const int* sel = (s & 1) ? sel_q : sel_p;
    __shared__ int sidx[64];
    __shared__ uint buf[64][33];
    int tid = threadIdx.x;
    if (tid < 64) sidx[tid] = sel[(dir * B + tid) * K + j];
    __syncthreads();
    int rb = tid >> 2, u = tid & 3;     // read mapping: row rb, quarter u
    const ushort* srow = xT + (((size_t)whichsrc * B + rb) * HW + sidx[rb]) * C;
    int wv = tid >> 6, lb = tid & 63;   // write mapping: lane = b
    ushort* obase = XgT + (size_t)s * C * NLOC + (size_t)j * 64 + lb;
    for (int ch = 0; ch < 12; ++ch) {
        __syncthreads();
        uint4 v0 = *(const uint4*)(srow + ch * 64 + u * 8);
        uint4 v1 = *(const uint4*)(srow + ch * 64 + (u + 4) * 8);
        buf[rb][u * 4 + 0] = v0.x; buf[rb][u * 4 + 1] = v0.y;
        buf[rb][u * 4 + 2] = v0.z; buf[rb][u * 4 + 3] = v0.w;
        buf[rb][(u + 4) * 4 + 0] = v1.x; buf[rb][(u + 4) * 4 + 1] = v1.y;
        buf[rb][(u + 4) * 4 + 2] = v1.z; buf[rb][(u + 4) * 4 + 3] = v1.w;
        __syncthreads();
#pragma unroll
        for (int st = 0; st < 16; ++st) {
            int cl = wv + st * 4;
            uint uv = buf[lb][cl >> 1];
            ushort val = (cl & 1) ? (ushort)(uv >> 16) : (ushort)(uv & 0xffffu);
            obase[(size_t)(ch * 64 + cl) * NLOC] = val;
        }
    }
}

// ---------- Mp[mat][split] = partial X^T X via MFMA, 128x128 tile, split-K=5 ----------
__global__ __launch_bounds__(256) void ata_mfma(const ushort* __restrict__ XgT,
                                                float* __restrict__ Mp) {
    int bx = blockIdx.x;                 // 0..35
    int mat = blockIdx.y, split = blockIdx.z;
    int rt = bx / 6, ct = bx % 6;
    const ushort* X = XgT + (size_t)mat * C * NLOC;

    __shared__ ull pool[4096];           // 32768 B
    char* As = (char*)pool;
    char* Bs = As + 16384;

    int tid = threadIdx.x;
    int w = tid >> 6, l = tid & 63;
    int quad = l >> 4, col = l & 15;
    int lrow = l >> 2, pos = l & 3;

    const ushort* gA[2][2]; const ushort* gB[2][2];
    char* dA[2][2]; char* dB[2][2];
#pragma unroll
    for (int n = 0; n < 2; ++n) {
        int sm = w * 32 + n * 16 + lrow;
        int cdat = pos ^ ((sm >> 1) & 3);
#pragma unroll
        for (int s = 0; s < 2; ++s) {
            gA[s][n] = X + (size_t)(rt * 128 + sm) * NLOC + split * 640 + s * 32 + cdat * 8;
            gB[s][n] = X + (size_t)(ct * 128 + sm) * NLOC + split * 640 + s * 32 + cdat * 8;
            dA[s][n] = As + s * 8192 + w * 2048 + n * 1024;
            dB[s][n] = Bs + s * 8192 + w * 2048 + n * 1024;
        }
    }

    int offA[4], offB[4];
#pragma unroll
    for (int i = 0; i < 4; ++i) {
        int m_loc = (w >> 1) * 64 + i * 16 + col;
        offA[i] = m_loc * 64 + ((quad ^ ((m_loc >> 1) & 3)) * 16);
        int n_loc = (w & 1) * 64 + i * 16 + col;
        offB[i] = n_loc * 64 + ((quad ^ ((n_loc >> 1) & 3)) * 16);
    }

    floatx4 zero = {0.f, 0.f, 0.f, 0.f};
    floatx4 acc[4][4];
#pragma unroll
    for (int i = 0; i < 4; ++i)
#pragma unroll
        for (int j = 0; j < 4; ++j) acc[i][j] = zero;

    gemm_pp<10>(gA, gB, dA, dB, As, Bs, offA, offB, acc);

    float* Mo = Mp + (size_t)(mat * 5 + split) * C * C;
#pragma unroll
    for (int i = 0; i < 4; ++i)
#pragma unroll
        for (int j = 0; j < 4; ++j)
#pragma unroll
            for (int r = 0; r < 4; ++r) {
                int row = rt * 128 + (w >> 1) * 64 + i * 16 + quad * 4 + r;
                int cc  = ct * 128 + (w & 1) * 64 + j * 16 + col;
                Mo[(size_t)row * C + cc] = acc[i][j][r];
            }
}

// ---------- reduce Mp splits -> M (mats 0..3) ----------
__global__ __launch_bounds__(256) void reduce_mp(const float* __restrict__ Mp,
                                                 float* __restrict__ M) {
    int mat = blockIdx.y;
    int i = blockIdx.x * 256 + threadIdx.x;            // float4 index, 0..147455
    float4 r = {0.f, 0.f, 0.f, 0.f};
#pragma unroll
    for (int s = 0; s < 5; ++s) {
        const float4* a = (const float4*)(Mp + (size_t)(mat * 5 + s) * C * C);
        float4 v = a[i];
        r.x += v.x; r.y += v.y; r.z += v.z; r.w += v.w;
    }
    ((float4*)(M + (size_t)mat * C * C))[i] = r;
}

// ---------- fp32 X^T X for pooled mats (4,5), n=64 ----------
__global__ __launch_bounds__(256) void ata_pooled(const float* __restrict__ p1,
                                                  const float* __restrict__ p2,
                                                  float* __restrict__ M) {
    int mat = 4 + blockIdx.z;
    const float* X = (mat == 4) ? p1 : p2;
    int n = B;
    float* Mo = M + (size_t)mat * C * C;
    int ct = blockIdx.x, rt = blockIdx.y;

    __shared__ float As[16][64];
    __shared__ float Bs[16][64];
    int tid = threadIdx.x;
    int tx = tid & 15, ty = tid >> 4;
    int lr = tid >> 4, lc = (tid & 15) * 4;

    float acc[4][4] = {};
    for (int k0 = 0; k0 < n; k0 += 16) {
        float4 av = *(const float4*)&X[(size_t)(k0 + lr) * C + rt * 64 + lc];
        float4 bv = *(const float4*)&X[(size_t)(k0 + lr) * C + ct * 64 + lc];
        __syncthreads();
        *(float4*)&As[lr][lc] = av;
        *(float4*)&Bs[lr][lc] = bv;
        __syncthreads();
#pragma unroll
        for (int kk = 0; kk < 16; ++kk) {
            float4 af = *(const float4*)&As[kk][ty * 4];
            float4 bf = *(const float4*)&Bs[kk][tx * 4];
            float a[4] = {af.x, af.y, af.z, af.w};
            float bb[4] = {bf.x, bf.y, bf.z, bf.w};
#pragma unroll
            for (int i = 0; i < 4; ++i)
#pragma unroll
                for (int j = 0; j < 4; ++j)
                    acc[i][j] = fmaf(a[i], bb[j], acc[i][j]);
        }
    }
#pragma unroll
    for (int i = 0; i < 4; ++i) {
        float4 o = {acc[i][0], acc[i][1], acc[i][2], acc[i][3]};
        *(float4*)&Mo[(size_t)(rt * 64 + ty * 4 + i) * C + ct * 64 + tx * 4] = o;
    }
}

// ---------- colsum for mats 0..3 from XgT (no atomics) ----------
__global__ __launch_bounds__(256) void colsum4_kernel(const ushort* __restrict__ XgT,
                                                      float* __restrict__ colsum) {
    int mat = blockIdx.y, cb = blockIdx.x * 4;
    int r = threadIdx.x >> 6, lane = threadIdx.x & 63;
    const ushort* row = XgT + ((size_t)mat * C + cb + r) * NLOC;
    float s = 0.f;
    for (int i = lane; i < NLOC; i += 64) s += bf2f(row[i]);
    for (int off = 32; off > 0; off >>= 1) s += __shfl_down(s, off, 64);
    if (lane == 0) colsum[mat * C + cb + r] = s;
}

// ---------- colsum pooled (no atomics) ----------
__global__ __launch_bounds__(256) void colsum_pooled(const float* __restrict__ p1,
                                                     const float* __restrict__ p2,
                                                     float* __restrict__ colsum) {
    int mat = 4 + blockIdx.y;
    const float* X = (mat == 4) ? p1 : p2;
    int c = blockIdx.x * 256 + threadIdx.x;
    float s = 0.f;
    for (int r = 0; r < B; ++r) s += X[(size_t)r * C + c];
    colsum[mat * C + c] = s;
}

// ---------- std term ----------
__global__ __launch_bounds__(256) void std_kernel(const float* __restrict__ M,
                                                  const float* __restrict__ colsum,
                                                  float* __restrict__ slots) {
    int mat = blockIdx.y;
    float n = (mat < 4) ? (float)NLOC : (float)B;
    int c = blockIdx.x * 256 + threadIdx.x;
    float r = 0.f;
    if (c < C) {
        float mcc = M[(size_t)mat * C * C + (size_t)c * C + c];
        float cs = colsum[mat * C + c];
        float var = (mcc - cs * cs / n) / (n - 1.0f);
        float sd = sqrtf(var + 1e-5f);
        float g = 1.0f - sd;
        r = g > 0.f ? g : 0.f;
    }
    __shared__ float s4[4];
    float t = blk_reduce_sum(r, s4);
    if (threadIdx.x == 0) atomicAdd(&slots[SLOT_STD + mat], t);
}

// ---------- cov term: 48 blocks x 16 rows per mat ----------
__global__ __launch_bounds__(256) void cov_kernel(const float* __restrict__ M,
                                                  const float* __restrict__ colsum,
                                                  float* __restrict__ slots) {
    int mat = blockIdx.y;
    float n = (mat < 4) ? (float)NLOC : (float)B;
    float invn1 = 1.0f / (n - 1.0f);
    const float* Mm = M + (size_t)mat * C * C;
    __shared__ float cs_s[C];
    for (int c = threadIdx.x; c < C; c += 256) cs_s[c] = colsum[mat * C + c];
    __syncthreads();
    float s = 0.f;
    int r0 = blockIdx.x * 16;
    for (int r = 0; r < 16; ++r) {
        int row = r0 + r;
        float csr = cs_s[row] / n;
        const float* Mr = Mm + (size_t)row * C;
        for (int c = threadIdx.x; c < C; c += 256) {
            float cv = (Mr[c] - csr * cs_s[c]) * invn1;
            if (c != row) s = fmaf(cv, cv, s);
        }
    }
    __shared__ float s4[4];
    float t = blk_reduce_sum(s, s4);
    if (threadIdx.x == 0) atomicAdd(&slots[SLOT_COV + mat], t);
}

// ---------- invariance terms ----------
__global__ __launch_bounds__(256) void inv_global_kernel(const float* __restrict__ p1,
                                                         const float* __restrict__ p2,
                                                         float* __restrict__ slots) {
    int idx = blockIdx.x * 256 + threadIdx.x;
    int stride = gridDim.x * 256;
    float s = 0.f;
    for (int i = idx; i < B * C; i += stride) {
        float d = p1[i] - p2[i];
        s = fmaf(d, d, s);
    }
    __shared__ float s4[4];
    float t = blk_reduce_sum(s, s4);
    if (threadIdx.x == 0) atomicAdd(&slots[SLOT_INVG], t);
}

__global__ __launch_bounds__(256) void inv_local2(const ushort* __restrict__ XgT,
                                                  float* __restrict__ slots) {
    int pair = blockIdx.y;
    const uint* A4 = (const uint*)(XgT + (size_t)(2 * pair) * C * NLOC);
    const uint* B4 = (const uint*)(XgT + (size_t)(2 * pair + 1) * C * NLOC);
    int idx = blockIdx.x * 256 + threadIdx.x;
    int stride = gridDim.x * 256;
    int n = C * NLOC / 2;
    float s = 0.f;
    for (int i = idx; i < n; i += stride) {
        uint ua = A4[i], ub = B4[i];
        float d0 = bf2f_lo(ua) - bf2f_lo(ub);
        float d1 = bf2f_hi(ua) - bf2f_hi(ub);
        s = fmaf(d0, d0, s);
        s = fmaf(d1, d1, s);
    }
    __shared__ float s4[4];
    float t = blk_reduce_sum(s, s4);
    if (threadIdx.x == 0) atomicAdd(&slots[(pair == 0) ? SLOT_INV1 : SLOT_INV2], t);
}

// ---------- final combine ----------
__global__ void final_kernel(const float* __restrict__ slots, float* __restrict__ out) {
    float std_t[6], cov_t[6];
    for (int m = 0; m < 6; ++m) {
        std_t[m] = slots[SLOT_STD + m] / (float)C * 0.5f;
        cov_t[m] = slots[SLOT_COV + m] / (float)C;
    }
    float inv_g = slots[SLOT_INVG] / (float)(B * C);
    float global_loss = 25.0f * inv_g + 25.0f * (std_t[4] + std_t[5]) + (cov_t[4] + cov_t[5]);
    float inv1 = 25.0f * slots[SLOT_INV1] / (float)(NLOC * C);
    float inv2 = 25.0f * slots[SLOT_INV2] / (float)(NLOC * C);
    float var1 = 25.0f * (std_t[0] + std_t[1]);
    float var2 = 25.0f * (std_t[2] + std_t[3]);
    float cov1 = cov_t[0] + cov_t[1];
    float cov2 = cov_t[2] + cov_t[3];
    float local_loss = (inv1 + inv2) * 0.5f + (var1 + var2) * 0.5f + (cov1 + cov2) * 0.5f;
    out[0] = 0.5f * global_loss + 0.5f * local_loss;
}

extern "C" void kernel_launch(void* const* d_in, const int* in_sizes, int n_in,
                              void* d_out, int out_size, void* d_ws, size_t ws_size,
                              hipStream_t stream) {
    const float* spatial_1 = (const float*)d_in[0];
    const float* pooled_1  = (const float*)d_in[1];
    const float* spatial_2 = (const float*)d_in[2];
    const float* pooled_2  = (const float*)d_in[3];
    float* out = (float*)d_out;

    char* ws = (char*)d_ws;
    float*  slots  = (float*)(ws + OFF_SLOTS);
    float*  colsum = (float*)(ws + OFF_COLSUM);
    ull*    nn1    = (ull*)(ws + OFF_NN1);
    ull*    nn2    = (ull*)(ws + OFF_NN2);
    int*    sel_p  = (int*)(ws + OFF_SELP);
    int*    sel_q  = (int*)(ws + OFF_SELQ);
    float*  norm   = (float*)(ws + OFF_NORM);
    ushort* xT     = (ushort*)(ws + OFF_XT);
    float*  Mp     = (float*)(ws + OFF_MP);   // overlays xT (dead after gather)
    ushort* XgT    = (ushort*)(ws + OFF_XGT);
    float*  M      = (float*)(ws + OFF_M);

    hipMemsetAsync(ws, 0, OFF_NN1, stream);                          // slots + colsum
    hipMemsetAsync(ws + OFF_NN1, 0xFF, OFF_SELP - OFF_NN1, stream);  // nn keys
    // norm memset no longer needed: convert_kernel writes every element exactly once

    convert_kernel<<<dim3(9, 128), 256, 0, stream>>>(spatial_1, spatial_2, xT, norm);
    cdist_mfma<<<1600, 256, 0, stream>>>(xT, norm, nn1, nn2);
    select_topk_wave<<<dim3(B, 2), 64, 0, stream>>>(nn1, nn2, sel_p, sel_q);
    gather_jmajor<<<dim3(K, 4), 256, 0, stream>>>(xT, sel_p, sel_q, XgT);
    ata_mfma<<<dim3(36, 4, 5), 256, 0, stream>>>(XgT, Mp);
    ata_pooled<<<dim3(12, 12, 2), 256, 0, stream>>>(pooled_1, pooled_2, M);
    reduce_mp<<<dim3(576, 4), 256, 0, stream>>>(Mp, M);
    colsum4_kernel<<<dim3(192, 4), 256, 0, stream>>>(XgT, colsum);
    colsum_pooled<<<dim3(3, 2), 256, 0, stream>>>(pooled_1, pooled_2, colsum);
    std_kernel<<<dim3(3, 6), 256, 0, stream>>>(M, colsum, slots);
    cov_kernel<<<dim3(48, 6), 256, 0, stream>>>(M, colsum, slots);
    inv_global_kernel<<<dim3(96), 256, 0, stream>>>(pooled_1, pooled_2, slots);
    inv_local2<<<dim3(300, 2), 256, 0, stream>>>(XgT, slots);
    final_kernel<<<1, 1, 0, stream>>>(slots, out);
}

// Round 3
// 472.887 us; speedup vs baseline: 1.0219x; 1.0147x over previous
//
#include <hip/hip_runtime.h>
#include <stdint.h>

typedef unsigned long long ull;
typedef unsigned int uint;
typedef unsigned short ushort;

typedef __attribute__((ext_vector_type(8))) short short8;
typedef __attribute__((ext_vector_type(4))) float floatx4;

#define B   64
#define C   768
#define HW  576
#define K   50
#define NLOC (B*K)          // 3200

// ---- workspace layout (bytes) ----
#define OFF_SLOTS   0            // 64 floats
#define OFF_COLSUM  256          // 6*768*4 = 18432
#define OFF_NN1     18688        // 64*576*8 = 294912
#define OFF_NN2     313600       // 294912
#define OFF_SELP    608512       // 2*64*50*4 = 25600
#define OFF_SELQ    634112       // 25600
#define OFF_NORM    659712       // (unused in v4; norm partials live in M region)
#define OFF_XT      954624       // 2*64*576*768*2 = 113246208  (dead after gather -> reused as Mp)
#define OFF_MP      OFF_XT       // 4 mats * 5 splits * 768*768*4 = 47185920 (fits in XT region)
#define OFF_XGT     114200832    // 4*768*3200*2 = 19660800
#define OFF_M       133861632    // 6*768*768*4 = 14155776
// norm partials [2 halves][2*64][576] f32 = 589824 B overlay at OFF_M:
// written by convert, read by cdist, M itself is written only later (reduce_mp/ata_pooled)
// total 148017408

#define SLOT_INVG 0
#define SLOT_STD  1   // +mat (0..5)
#define SLOT_COV  7   // +mat (0..5)
#define SLOT_INV1 13
#define SLOT_INV2 14

__device__ __forceinline__ ull umin64(ull a, ull b) { return a < b ? a : b; }

__device__ __forceinline__ float bf2f_lo(uint u) { return __uint_as_float(u << 16); }
__device__ __forceinline__ float bf2f_hi(uint u) { return __uint_as_float(u & 0xffff0000u); }
__device__ __forceinline__ float bf2f(ushort u) { return __uint_as_float(((uint)u) << 16); }

__device__ __forceinline__ ushort f2bf(float f) {
    uint u = __float_as_uint(f);
    uint r = (u + 0x7fffu + ((u >> 16) & 1u)) >> 16;   // RNE
    return (ushort)r;
}

__device__ __forceinline__ float blk_reduce_sum(float v, float* s4) {
    for (int off = 32; off > 0; off >>= 1) v += __shfl_down(v, off, 64);
    int lane = threadIdx.x & 63, w = threadIdx.x >> 6;
    if (lane == 0) s4[w] = v;
    __syncthreads();
    float r = 0.f;
    if (threadIdx.x == 0) r = s4[0] + s4[1] + s4[2] + s4[3];
    return r;
}

// ---------- convert fp32 [b][c][p] -> bf16 xT[which][b][p][c] + fused norm partials ----------
// v4: write-contiguity version. Block = (64p x 384c). Strided float4 reads (pattern proven
//     irrelevant in v1-v3), 4x4 register transpose -> bf16 LDS tile [64][392], single barrier,
//     write-out 12 x 4KB wave-contiguous stores (768B per p-row segment vs 128B in v1-v3).
//     Norm partial per (half): no atomics, no memset; stored in M-region overlay.
__global__ __launch_bounds__(256) void convert_kernel(const float* __restrict__ x1,
                                                      const float* __restrict__ x2,
                                                      ushort* __restrict__ xT,
                                                      float* __restrict__ normp) {
    int z = blockIdx.y;
    int which = z >> 6, b = z & 63;
    int half = blockIdx.x & 1;
    int pt = blockIdx.x >> 1;          // 0..8
    int p0 = pt * 64, c0 = half * 384;
    const float* X = (which ? x2 : x1) + ((size_t)b * C + c0) * HW + p0;

    __shared__ ushort tile[64][392];   // [p][c], 784B row stride
    __shared__ float nlds[64][4];

    int t = threadIdx.x;
    int pq = t & 15, cq = t >> 4;      // p-quad (16), c-quad (16)
    int w = t >> 6;

    float ss[4] = {0.f, 0.f, 0.f, 0.f};

#pragma unroll
    for (int pass = 0; pass < 6; ++pass) {
        floatx4 v[4];
#pragma unroll
        for (int i = 0; i < 4; ++i)
            v[i] = *(const floatx4*)(X + (size_t)(pass * 64 + 4 * cq + i) * HW + 4 * pq);
#pragma unroll
        for (int j = 0; j < 4; ++j) {
            ushort u0 = f2bf(v[0][j]), u1 = f2bf(v[1][j]);
            ushort u2 = f2bf(v[2][j]), u3 = f2bf(v[3][j]);
            ushort4 uu; uu.x = u0; uu.y = u1; uu.z = u2; uu.w = u3;
            *(ushort4*)&tile[4 * pq + j][pass * 64 + 4 * cq] = uu;
            float r0 = bf2f(u0), r1 = bf2f(u1), r2 = bf2f(u2), r3 = bf2f(u3);
            ss[j] = fmaf(r0, r0, ss[j]); ss[j] = fmaf(r1, r1, ss[j]);
            ss[j] = fmaf(r2, r2, ss[j]); ss[j] = fmaf(r3, r3, ss[j]);
        }
    }
    // reduce ss over the wave's 4 local c-quads (lanes l, l^16, l^32, l^48 share pq)
#pragma unroll
    for (int j = 0; j < 4; ++j) {
        ss[j] += __shfl_xor(ss[j], 16, 64);
        ss[j] += __shfl_xor(ss[j], 32, 64);
    }
    if ((t & 63) < 16) {
#pragma unroll
        for (int j = 0; j < 4; ++j) nlds[4 * pq + j][w] = ss[j];
    }
    __syncthreads();

    // write-out: 12 steps x (256 lanes x 16B) = 4KB contiguous per step
    ushort* dst = xT + (((size_t)which * B + b) * HW + p0) * C + c0;
    const char* tb = (const char*)tile;
#pragma unroll
    for (int step = 0; step < 12; ++step) {
        int ib = (step * 256 + t) * 16;
        int p = ib / 768, cb = ib % 768;
        short8 vv = *(const short8*)(tb + (size_t)p * 784 + cb);
        *(short8*)(dst + (size_t)p * C + (cb >> 1)) = vv;
    }
    if (t < 64) {
        float nv = nlds[t][0] + nlds[t][1] + nlds[t][2] + nlds[t][3];
        normp[((size_t)half * 128 + which * 64 + b) * HW + p0 + t] = nv;
    }
}

// ---------- shared ping-pong MFMA K-loop (counted vmcnt + raw barriers) ----------
template<int NK>
__device__ __forceinline__ void gemm_pp(const ushort* (&gA)[2][2], const ushort* (&gB)[2][2],
                                        char* (&dA)[2][2], char* (&dB)[2][2],
                                        const char* As, const char* Bs,
                                        const int (&offA)[4], const int (&offB)[4],
                                        floatx4 (&acc)[4][4]) {
    auto issue = [&](int s, int k0) {
#pragma unroll
        for (int n = 0; n < 2; ++n) {
            __builtin_amdgcn_global_load_lds(
                (const __attribute__((address_space(1))) void*)(gA[s][n] + k0),
                (__attribute__((address_space(3))) void*)dA[s][n], 16, 0, 0);
            __builtin_amdgcn_global_load_lds(
                (const __attribute__((address_space(1))) void*)(gB[s][n] + k0),
                (__attribute__((address_space(3))) void*)dB[s][n], 16, 0, 0);
        }
    };
    auto compute = [&](int s) {
        short8 a[4], bb[4];
#pragma unroll
        for (int i = 0; i < 4; ++i) a[i] = *(const short8*)(As + s * 8192 + offA[i]);
#pragma unroll
        for (int j = 0; j < 4; ++j) bb[j] = *(const short8*)(Bs + s * 8192 + offB[j]);
#pragma unroll
        for (int i = 0; i < 4; ++i)
#pragma unroll
            for (int j = 0; j < 4; ++j)
                acc[i][j] = __builtin_amdgcn_mfma_f32_16x16x32_bf16(a[i], bb[j], acc[i][j], 0, 0, 0);
    };

    issue(0, 0);
    issue(1, 0);
    for (int k = 0; k < NK; ++k) {
        asm volatile("s_waitcnt vmcnt(4)" ::: "memory");   // own s0(k) loads done
        __builtin_amdgcn_s_barrier();
        __builtin_amdgcn_sched_barrier(0);
        compute(0);
        __builtin_amdgcn_sched_barrier(0);
        __builtin_amdgcn_s_barrier();                      // all waves done reading s0
        if (k + 1 < NK) {
            issue(0, (k + 1) * 64);
            asm volatile("s_waitcnt vmcnt(4)" ::: "memory");  // own s1(k) loads done
        } else {
            asm volatile("s_waitcnt vmcnt(0)" ::: "memory");  // tail: drain s1(NK-1)
        }
        __builtin_amdgcn_s_barrier();
        __builtin_amdgcn_sched_barrier(0);
        compute(1);
        __builtin_amdgcn_sched_barrier(0);
        __builtin_amdgcn_s_barrier();                      // all waves done reading s1
        if (k + 1 < NK) issue(1, (k + 1) * 64);
    }
}

// ---------- cdist Gram via MFMA, 128x128 tile, XCD-swizzled 1-D grid ----------
__global__ __launch_bounds__(256) void cdist_mfma(const ushort* __restrict__ xT,
                                                  const float* __restrict__ normp,
                                                  ull* __restrict__ nn1,
                                                  ull* __restrict__ nn2) {
    int id = blockIdx.x;
    int xcd = id & 7, slot = id >> 3;
    int b = xcd + 8 * (slot / 25);      // all 25 tiles of a batch share one XCD slot
    int t = slot % 25;
    int qt = t % 5, pt = t / 5;

    const ushort* X1 = xT + (size_t)b * HW * C;
    const ushort* X2 = xT + (size_t)(B + b) * HW * C;

    __shared__ ull pool[4224];          // 33792 B: A(16384)+B(16384); red overlays
    char* As = (char*)pool;
    char* Bs = As + 16384;

    int tid = threadIdx.x;
    int w = tid >> 6, l = tid & 63;
    int quad = l >> 4, col = l & 15;
    int lrow = l >> 2, pos = l & 3;

    const ushort* gA[2][2]; const ushort* gB[2][2];
    char* dA[2][2]; char* dB[2][2];
#pragma unroll
    for (int n = 0; n < 2; ++n) {
        int sm = w * 32 + n * 16 + lrow;            // LDS row 0..127
        int cdat = pos ^ ((sm >> 1) & 3);
        int p = pt * 128 + sm; if (p >= HW) p = HW - 1;
        int q = qt * 128 + sm; if (q >= HW) q = HW - 1;
#pragma unroll
        for (int s = 0; s < 2; ++s) {
            gA[s][n] = X1 + (size_t)p * C + s * 32 + cdat * 8;
            gB[s][n] = X2 + (size_t)q * C + s * 32 + cdat * 8;
            dA[s][n] = As + s * 8192 + w * 2048 + n * 1024;
            dB[s][n] = Bs + s * 8192 + w * 2048 + n * 1024;
        }
    }

    int offA[4], offB[4];
#pragma unroll
    for (int i = 0; i < 4; ++i) {
        int m_loc = (w >> 1) * 64 + i * 16 + col;
        offA[i] = m_loc * 64 + ((quad ^ ((m_loc >> 1) & 3)) * 16);
        int n_loc = (w & 1) * 64 + i * 16 + col;
        offB[i] = n_loc * 64 + ((quad ^ ((n_loc >> 1) & 3)) * 16);
    }

    floatx4 zero = {0.f, 0.f, 0.f, 0.f};
    floatx4 acc[4][4];
#pragma unroll
    for (int i = 0; i < 4; ++i)
#pragma unroll
        for (int j = 0; j < 4; ++j) acc[i][j] = zero;

    gemm_pp<12>(gA, gB, dA, dB, As, Bs, offA, offB, acc);

    // norms: sum of the two c-half partials
    const float* n1a = normp + (size_t)b * HW;
    const float* n1b = normp + (size_t)(128 + b) * HW;
    const float* n2a = normp + (size_t)(64 + b) * HW;
    const float* n2b = normp + (size_t)(192 + b) * HW;
    float n1v[4][4]; bool vp[4][4];
    float n2v[4];    bool vq[4];
#pragma unroll
    for (int i = 0; i < 4; ++i)
#pragma unroll
        for (int r = 0; r < 4; ++r) {
            int p = pt * 128 + (w >> 1) * 64 + i * 16 + quad * 4 + r;
            vp[i][r] = (p < HW);
            int pc = p < HW ? p : (HW - 1);
            n1v[i][r] = n1a[pc] + n1b[pc];
        }
#pragma unroll
    for (int j = 0; j < 4; ++j) {
        int q = qt * 128 + (w & 1) * 64 + j * 16 + col;
        vq[j] = (q < HW);
        int qc = q < HW ? q : (HW - 1);
        n2v[j] = n2a[qc] + n2b[qc];
    }

    __syncthreads();
    typedef ull row33[33];
    row33* red = (row33*)pool;

    // pass 1: per-p min over q
#pragma unroll
    for (int i = 0; i < 4; ++i)
#pragma unroll
        for (int r = 0; r < 4; ++r) {
            int p_loc = (w >> 1) * 64 + i * 16 + quad * 4 + r;
            ull best = ~0ull;
#pragma unroll
            for (int j = 0; j < 4; ++j) {
                if (!vq[j]) continue;
                float d2 = fmaxf(n1v[i][r] + n2v[j] - 2.0f * acc[i][j][r], 0.0f);
                unsigned q_glob = qt * 128 + (w & 1) * 64 + j * 16 + col;
                best = umin64(best, ((ull)__float_as_uint(d2) << 32) | q_glob);
            }
            red[p_loc][(w & 1) * 16 + col] = best;
        }
    __syncthreads();
    if (tid < 128) {
        int p_glob = pt * 128 + tid;
        ull m = ~0ull;
#pragma unroll
        for (int x = 0; x < 32; ++x) m = umin64(m, red[tid][x]);
        if (p_glob < HW) atomicMin(&nn1[(size_t)b * HW + p_glob], m);
    }
    __syncthreads();
    // pass 2: per-q min over p
#pragma unroll
    for (int j = 0; j < 4; ++j) {
        int q_loc = (w & 1) * 64 + j * 16 + col;
        ull best = ~0ull;
#pragma unroll
        for (int i = 0; i < 4; ++i)
#pragma unroll
            for (int r = 0; r < 4; ++r) {
                if (!vp[i][r]) continue;
                float d2 = fmaxf(n1v[i][r] + n2v[j] - 2.0f * acc[i][j][r], 0.0f);
                unsigned p_glob = pt * 128 + (w >> 1) * 64 + i * 16 + quad * 4 + r;
                best = umin64(best, ((ull)__float_as_uint(d2) << 32) | p_glob);
            }
        red[q_loc][(w >> 1) * 4 + quad] = best;
    }
    __syncthreads();
    if (tid < 128) {
        int q_glob = qt * 128 + tid;
        ull m = ~0ull;
#pragma unroll
        for (int x = 0; x < 8; ++x) m = umin64(m, red[tid][x]);
        if (q_glob < HW) atomicMin(&nn2[(size_t)b * HW + q_glob], m);
    }
}

// ---------- top-k: one wave per (b,dir), keys in registers ----------
__global__ __launch_bounds__(64) void select_topk_wave(const ull* __restrict__ nn1,
                                                       const ull* __restrict__ nn2,
                                                       int* __restrict__ sel_p,
                                                       int* __restrict__ sel_q) {
    int b = blockIdx.x, dir = blockIdx.y;
    const ull* nn = dir ? nn2 : nn1;
    int lane = threadIdx.x;
    ull key[9]; uint qv[9];
#pragma unroll
    for (int r = 0; r < 9; ++r) {
        int p = r * 64 + lane;
        ull e = nn[(size_t)b * HW + p];
        key[r] = (e & 0xFFFFFFFF00000000ull) | (unsigned)p;
        qv[r] = (uint)(e & 0xFFFFFFFFu);
    }
    int* sp = sel_p + (dir * B + b) * K;
    int* sq = sel_q + (dir * B + b) * K;
    for (int it = 0; it < K; ++it) {
        ull m = key[0];
#pragma unroll
        for (int r = 1; r < 9; ++r) m = umin64(m, key[r]);
#pragma unroll
        for (int off = 32; off > 0; off >>= 1) m = umin64(m, __shfl_xor(m, off, 64));
#pragma unroll
        for (int r = 0; r < 9; ++r) {
            if (key[r] == m) {
                sp[it] = (int)(uint)(m & 0xFFFFFFFFu);
                sq[it] = (int)qv[r];
                key[r] = ~0ull;
            }
        }
    }
}

// ---------- gather into XgT[s][c][i], i = j*64 + b (coalesced writes) ----------
// s: 0=x1[sel_p d0] 1=x2[sel_q d0] 2=x2[sel_p d1] 3=x1[sel_q d1]
__global__ __launch_bounds__(256) void gather_jmajor(const ushort* __restrict__ xT,
                                                     const int* __restrict__ sel_p,
                                                     const int* __restrict__ sel_q,
                                                     ushort* __restrict__ XgT) {
    int j = blockIdx.x, s = blockIdx.y;
    int dir = s >> 1;
    int whichsrc = (s == 1 || s == 2) ? 1 : 0;
    const int* sel = (s & 1) ? sel_q : sel_p;
    __shared__ int sidx[64];
    __shared__ uint buf[64][33];
    int tid = threadIdx.x;
    if (tid < 64) sidx[tid] = sel[(dir * B + tid) * K + j];
    __syncthreads();
    int rb = tid >> 2, u = tid & 3;     // read mapping: row rb, quarter u
    const ushort* srow = xT + (((size_t)whichsrc * B + rb) * HW + sidx[rb]) * C;
    int wv = tid >> 6, lb = tid & 63;   // write mapping: lane = b
    ushort* obase = XgT + (size_t)s * C * NLOC + (size_t)j * 64 + lb;
    for (int ch = 0; ch < 12; ++ch) {
        __syncthreads();
        uint4 v0 = *(const uint4*)(srow + ch * 64 + u * 8);
        uint4 v1 = *(const uint4*)(srow + ch * 64 + (u + 4) * 8);
        buf[rb][u * 4 + 0] = v0.x; buf[rb][u * 4 + 1] = v0.y;
        buf[rb][u * 4 + 2] = v0.z; buf[rb][u * 4 + 3] = v0.w;
        buf[rb][(u + 4) * 4 + 0] = v1.x; buf[rb][(u + 4) * 4 + 1] = v1.y;
        buf[rb][(u + 4) * 4 + 2] = v1.z; buf[rb][(u + 4) * 4 + 3] = v1.w;
        __syncthreads();
#pragma unroll
        for (int st = 0; st < 16; ++st) {
            int cl = wv + st * 4;
            uint uv = buf[lb][cl >> 1];
            ushort val = (cl & 1) ? (ushort)(uv >> 16) : (ushort)(uv & 0xffffu);
            obase[(size_t)(ch * 64 + cl) * NLOC] = val;
        }
    }
}

// ---------- Mp[mat][split] = partial X^T X via MFMA, 128x128 tile, split-K=5 ----------
__global__ __launch_bounds__(256) void ata_mfma(const ushort* __restrict__ XgT,
                                                float* __restrict__ Mp) {
    int bx = blockIdx.x;                 // 0..35
    int mat = blockIdx.y, split = blockIdx.z;
    int rt = bx / 6, ct = bx % 6;
    const ushort* X = XgT + (size_t)mat * C * NLOC;

    __shared__ ull pool[4096];           // 32768 B
    char* As = (char*)pool;
    char* Bs = As + 16384;

    int tid = threadIdx.x;
    int w = tid >> 6, l = tid & 63;
    int quad = l >> 4, col = l & 15;
    int lrow = l >> 2, pos = l & 3;

    const ushort* gA[2][2]; const ushort* gB[2][2];
    char* dA[2][2]; char* dB[2][2];
#pragma unroll
    for (int n = 0; n < 2; ++n) {
        int sm = w * 32 + n * 16 + lrow;
        int cdat = pos ^ ((sm >> 1) & 3);
#pragma unroll
        for (int s = 0; s < 2; ++s) {
            gA[s][n] = X + (size_t)(rt * 128 + sm) * NLOC + split * 640 + s * 32 + cdat * 8;
            gB[s][n] = X + (size_t)(ct * 128 + sm) * NLOC + split * 640 + s * 32 + cdat * 8;
            dA[s][n] = As + s * 8192 + w * 2048 + n * 1024;
            dB[s][n] = Bs + s * 8192 + w * 2048 + n * 1024;
        }
    }

    int offA[4], offB[4];
#pragma unroll
    for (int i = 0; i < 4; ++i) {
        int m_loc = (w >> 1) * 64 + i * 16 + col;
        offA[i] = m_loc * 64 + ((quad ^ ((m_loc >> 1) & 3)) * 16);
        int n_loc = (w & 1) * 64 + i * 16 + col;
        offB[i] = n_loc * 64 + ((quad ^ ((n_loc >> 1) & 3)) * 16);
    }

    floatx4 zero = {0.f, 0.f, 0.f, 0.f};
    floatx4 acc[4][4];
#pragma unroll
    for (int i = 0; i < 4; ++i)
#pragma unroll
        for (int j = 0; j < 4; ++j) acc[i][j] = zero;

    gemm_pp<10>(gA, gB, dA, dB, As, Bs, offA, offB, acc);

    float* Mo = Mp + (size_t)(mat * 5 + split) * C * C;
#pragma unroll
    for (int i = 0; i < 4; ++i)
#pragma unroll
        for (int j = 0; j < 4; ++j)
#pragma unroll
            for (int r = 0; r < 4; ++r) {
                int row = rt * 128 + (w >> 1) * 64 + i * 16 + quad * 4 + r;
                int cc  = ct * 128 + (w & 1) * 64 + j * 16 + col;
                Mo[(size_t)row * C + cc] = acc[i][j][r];
            }
}

// ---------- reduce Mp splits -> M (mats 0..3) ----------
__global__ __launch_bounds__(256) void reduce_mp(const float* __restrict__ Mp,
                                                 float* __restrict__ M) {
    int mat = blockIdx.y;
    int i = blockIdx.x * 256 + threadIdx.x;            // float4 index, 0..147455
    float4 r = {0.f, 0.f, 0.f, 0.f};
#pragma unroll
    for (int s = 0; s < 5; ++s) {
        const float4* a = (const float4*)(Mp + (size_t)(mat * 5 + s) * C * C);
        float4 v = a[i];
        r.x += v.x; r.y += v.y; r.z += v.z; r.w += v.w;
    }
    ((float4*)(M + (size_t)mat * C * C))[i] = r;
}

// ---------- fp32 X^T X for pooled mats (4,5), n=64 ----------
__global__ __launch_bounds__(256) void ata_pooled(const float* __restrict__ p1,
                                                  const float* __restrict__ p2,
                                                  float* __restrict__ M) {
    int mat = 4 + blockIdx.z;
    const float* X = (mat == 4) ? p1 : p2;
    int n = B;
    float* Mo = M + (size_t)mat * C * C;
    int ct = blockIdx.x, rt = blockIdx.y;

    __shared__ float As[16][64];
    __shared__ float Bs[16][64];
    int tid = threadIdx.x;
    int tx = tid & 15, ty = tid >> 4;
    int lr = tid >> 4, lc = (tid & 15) * 4;

    float acc[4][4] = {};
    for (int k0 = 0; k0 < n; k0 += 16) {
        float4 av = *(const float4*)&X[(size_t)(k0 + lr) * C + rt * 64 + lc];
        float4 bv = *(const float4*)&X[(size_t)(k0 + lr) * C + ct * 64 + lc];
        __syncthreads();
        *(float4*)&As[lr][lc] = av;
        *(float4*)&Bs[lr][lc] = bv;
        __syncthreads();
#pragma unroll
        for (int kk = 0; kk < 16; ++kk) {
            float4 af = *(const float4*)&As[kk][ty * 4];
            float4 bf = *(const float4*)&Bs[kk][tx * 4];
            float a[4] = {af.x, af.y, af.z, af.w};
            float bb[4] = {bf.x, bf.y, bf.z, bf.w};
#pragma unroll
            for (int i = 0; i < 4; ++i)
#pragma unroll
                for (int j = 0; j < 4; ++j)
                    acc[i][j] = fmaf(a[i], bb[j], acc[i][j]);
        }
    }
#pragma unroll
    for (int i = 0; i < 4; ++i) {
        float4 o = {acc[i][0], acc[i][1], acc[i][2], acc[i][3]};
        *(float4*)&Mo[(size_t)(rt * 64 + ty * 4 + i) * C + ct * 64 + tx * 4] = o;
    }
}

// ---------- colsum for mats 0..3 from XgT (no atomics) ----------
__global__ __launch_bounds__(256) void colsum4_kernel(const ushort* __restrict__ XgT,
                                                      float* __restrict__ colsum) {
    int mat = blockIdx.y, cb = blockIdx.x * 4;
    int r = threadIdx.x >> 6, lane = threadIdx.x & 63;
    const ushort* row = XgT + ((size_t)mat * C + cb + r) * NLOC;
    float s = 0.f;
    for (int i = lane; i < NLOC; i += 64) s += bf2f(row[i]);
    for (int off = 32; off > 0; off >>= 1) s += __shfl_down(s, off, 64);
    if (lane == 0) colsum[mat * C + cb + r] = s;
}

// ---------- colsum pooled (no atomics) ----------
__global__ __launch_bounds__(256) void colsum_pooled(const float* __restrict__ p1,
                                                     const float* __restrict__ p2,
                                                     float* __restrict__ colsum) {
    int mat = 4 + blockIdx.y;
    const float* X = (mat == 4) ? p1 : p2;
    int c = blockIdx.x * 256 + threadIdx.x;
    float s = 0.f;
    for (int r = 0; r < B; ++r) s += X[(size_t)r * C + c];
    colsum[mat * C + c] = s;
}

// ---------- std term ----------
__global__ __launch_bounds__(256) void std_kernel(const float* __restrict__ M,
                                                  const float* __restrict__ colsum,
                                                  float* __restrict__ slots) {
    int mat = blockIdx.y;
    float n = (mat < 4) ? (float)NLOC : (float)B;
    int c = blockIdx.x * 256 + threadIdx.x;
    float r = 0.f;
    if (c < C) {
        float mcc = M[(size_t)mat * C * C + (size_t)c * C + c];
        float cs = colsum[mat * C + c];
        float var = (mcc - cs * cs / n) / (n - 1.0f);
        float sd = sqrtf(var + 1e-5f);
        float g = 1.0f - sd;
        r = g > 0.f ? g : 0.f;
    }
    __shared__ float s4[4];
    float t = blk_reduce_sum(r, s4);
    if (threadIdx.x == 0) atomicAdd(&slots[SLOT_STD + mat], t);
}

// ---------- cov term: 48 blocks x 16 rows per mat ----------
__global__ __launch_bounds__(256) void cov_kernel(const float* __restrict__ M,
                                                  const float* __restrict__ colsum,
                                                  float* __restrict__ slots) {
    int mat = blockIdx.y;
    float n = (mat < 4) ? (float)NLOC : (float)B;
    float invn1 = 1.0f / (n - 1.0f);
    const float* Mm = M + (size_t)mat * C * C;
    __shared__ float cs_s[C];
    for (int c = threadIdx.x; c < C; c += 256) cs_s[c] = colsum[mat * C + c];
    __syncthreads();
    float s = 0.f;
    int r0 = blockIdx.x * 16;
    for (int r = 0; r < 16; ++r) {
        int row = r0 + r;
        float csr = cs_s[row] / n;
        const float* Mr = Mm + (size_t)row * C;
        for (int c = threadIdx.x; c < C; c += 256) {
            float cv = (Mr[c] - csr * cs_s[c]) * invn1;
            if (c != row) s = fmaf(cv, cv, s);
        }
    }
    __shared__ float s4[4];
    float t = blk_reduce_sum(s, s4);
    if (threadIdx.x == 0) atomicAdd(&slots[SLOT_COV + mat], t);
}

// ---------- invariance terms ----------
__global__ __launch_bounds__(256) void inv_global_kernel(const float* __restrict__ p1,
                                                         const float* __restrict__ p2,
                                                         float* __restrict__ slots) {
    int idx = blockIdx.x * 256 + threadIdx.x;
    int stride = gridDim.x * 256;
    float s = 0.f;
    for (int i = idx; i < B * C; i += stride) {
        float d = p1[i] - p2[i];
        s = fmaf(d, d, s);
    }
    __shared__ float s4[4];
    float t = blk_reduce_sum(s, s4);
    if (threadIdx.x == 0) atomicAdd(&slots[SLOT_INVG], t);
}

__global__ __launch_bounds__(256) void inv_local2(const ushort* __restrict__ XgT,
                                                  float* __restrict__ slots) {
    int pair = blockIdx.y;
    const uint* A4 = (const uint*)(XgT + (size_t)(2 * pair) * C * NLOC);
    const uint* B4 = (const uint*)(XgT + (size_t)(2 * pair + 1) * C * NLOC);
    int idx = blockIdx.x * 256 + threadIdx.x;
    int stride = gridDim.x * 256;
    int n = C * NLOC / 2;
    float s = 0.f;
    for (int i = idx; i < n; i += stride) {
        uint ua = A4[i], ub = B4[i];
        float d0 = bf2f_lo(ua) - bf2f_lo(ub);
        float d1 = bf2f_hi(ua) - bf2f_hi(ub);
        s = fmaf(d0, d0, s);
        s = fmaf(d1, d1, s);
    }
    __shared__ float s4[4];
    float t = blk_reduce_sum(s, s4);
    if (threadIdx.x == 0) atomicAdd(&slots[(pair == 0) ? SLOT_INV1 : SLOT_INV2], t);
}

// ---------- final combine ----------
__global__ void final_kernel(const float* __restrict__ slots, float* __restrict__ out) {
    float std_t[6], cov_t[6];
    for (int m = 0; m < 6; ++m) {
        std_t[m] = slots[SLOT_STD + m] / (float)C * 0.5f;
        cov_t[m] = slots[SLOT_COV + m] / (float)C;
    }
    float inv_g = slots[SLOT_INVG] / (float)(B * C);
    float global_loss = 25.0f * inv_g + 25.0f * (std_t[4] + std_t[5]) + (cov_t[4] + cov_t[5]);
    float inv1 = 25.0f * slots[SLOT_INV1] / (float)(NLOC * C);
    float inv2 = 25.0f * slots[SLOT_INV2] / (float)(NLOC * C);
    float var1 = 25.0f * (std_t[0] + std_t[1]);
    float var2 = 25.0f * (std_t[2] + std_t[3]);
    float cov1 = cov_t[0] + cov_t[1];
    float cov2 = cov_t[2] + cov_t[3];
    float local_loss = (inv1 + inv2) * 0.5f + (var1 + var2) * 0.5f + (cov1 + cov2) * 0.5f;
    out[0] = 0.5f * global_loss + 0.5f * local_loss;
}

extern "C" void kernel_launch(void* const* d_in, const int* in_sizes, int n_in,
                              void* d_out, int out_size, void* d_ws, size_t ws_size,
                              hipStream_t stream) {
    const float* spatial_1 = (const float*)d_in[0];
    const float* pooled_1  = (const float*)d_in[1];
    const float* spatial_2 = (const float*)d_in[2];
    const float* pooled_2  = (const float*)d_in[3];
    float* out = (float*)d_out;

    char* ws = (char*)d_ws;
    float*  slots  = (float*)(ws + OFF_SLOTS);
    float*  colsum = (float*)(ws + OFF_COLSUM);
    ull*    nn1    = (ull*)(ws + OFF_NN1);
    ull*    nn2    = (ull*)(ws + OFF_NN2);
    int*    sel_p  = (int*)(ws + OFF_SELP);
    int*    sel_q  = (int*)(ws + OFF_SELQ);
    ushort* xT     = (ushort*)(ws + OFF_XT);
    float*  Mp     = (float*)(ws + OFF_MP);   // overlays xT (dead after gather)
    ushort* XgT    = (ushort*)(ws + OFF_XGT);
    float*  M      = (float*)(ws + OFF_M);
    float*  normp  = (float*)(ws + OFF_M);    // [2 halves][2*64][576] overlay, dead before M written

    hipMemsetAsync(ws, 0, OFF_NN1, stream);                          // slots + colsum
    hipMemsetAsync(ws + OFF_NN1, 0xFF, OFF_SELP - OFF_NN1, stream);  // nn keys

    convert_kernel<<<dim3(18, 128), 256, 0, stream>>>(spatial_1, spatial_2, xT, normp);
    cdist_mfma<<<1600, 256, 0, stream>>>(xT, normp, nn1, nn2);
    select_topk_wave<<<dim3(B, 2), 64, 0, stream>>>(nn1, nn2, sel_p, sel_q);
    gather_jmajor<<<dim3(K, 4), 256, 0, stream>>>(xT, sel_p, sel_q, XgT);
    ata_mfma<<<dim3(36, 4, 5), 256, 0, stream>>>(XgT, Mp);
    ata_pooled<<<dim3(12, 12, 2), 256, 0, stream>>>(pooled_1, pooled_2, M);
    reduce_mp<<<dim3(576, 4), 256, 0, stream>>>(Mp, M);
    colsum4_kernel<<<dim3(192, 4), 256, 0, stream>>>(XgT, colsum);
    colsum_pooled<<<dim3(3, 2), 256, 0, stream>>>(pooled_1, pooled_2, colsum);
    std_kernel<<<dim3(3, 6), 256, 0, stream>>>(M, colsum, slots);
    cov_kernel<<<dim3(48, 6), 256, 0, stream>>>(M, colsum, slots);
    inv_global_kernel<<<dim3(96), 256, 0, stream>>>(pooled_1, pooled_2, slots);
    inv_local2<<<dim3(300, 2), 256, 0, stream>>>(XgT, slots);
    final_kernel<<<1, 1, 0, stream>>>(slots, out);
}

// Round 4
// 470.250 us; speedup vs baseline: 1.0276x; 1.0056x over previous
//
#include <hip/hip_runtime.h>
#include <stdint.h>

typedef unsigned long long ull;
typedef unsigned int uint;
typedef unsigned short ushort;

typedef __attribute__((ext_vector_type(8))) short short8;
typedef __attribute__((ext_vector_type(4))) float floatx4;

#define B   64
#define C   768
#define HW  576
#define K   50
#define NLOC (B*K)          // 3200

// ---- workspace layout (bytes) ----
#define OFF_SLOTS   0            // 64 floats
#define OFF_COLSUM  256          // 6*768*4 = 18432
#define OFF_NN1     18688        // 64*576*8 = 294912
#define OFF_NN2     313600       // 294912
#define OFF_SELP    608512       // 2*64*50*4 = 25600
#define OFF_SELQ    634112       // 25600
#define OFF_XT      954624       // 2*64*576*768*2 = 113246208  (dead after gather -> reused as Mp)
#define OFF_MP      OFF_XT       // 4 mats * 5 splits * 768*768*4 = 47185920 (fits in XT region)
#define OFF_XGT     114200832    // 4*768*3200*2 = 19660800
#define OFF_M       133861632    // 6*768*768*4 = 14155776 (mats 4,5 used; 0-3 region = normp overlay)
// total 148017408

#define SLOT_INVG 0
#define SLOT_STD  1   // +mat (0..5)
#define SLOT_COV  7   // +mat (0..5)
#define SLOT_INV1 13
#define SLOT_INV2 14

__device__ __forceinline__ ull umin64(ull a, ull b) { return a < b ? a : b; }

__device__ __forceinline__ float bf2f_lo(uint u) { return __uint_as_float(u << 16); }
__device__ __forceinline__ float bf2f_hi(uint u) { return __uint_as_float(u & 0xffff0000u); }
__device__ __forceinline__ float bf2f(ushort u) { return __uint_as_float(((uint)u) << 16); }

__device__ __forceinline__ ushort f2bf(float f) {
    uint u = __float_as_uint(f);
    uint r = (u + 0x7fffu + ((u >> 16) & 1u)) >> 16;   // RNE
    return (ushort)r;
}

__device__ __forceinline__ float blk_reduce_sum(float v, float* s4) {
    for (int off = 32; off > 0; off >>= 1) v += __shfl_down(v, off, 64);
    int lane = threadIdx.x & 63, w = threadIdx.x >> 6;
    if (lane == 0) s4[w] = v;
    __syncthreads();
    float r = 0.f;
    if (threadIdx.x == 0) r = s4[0] + s4[1] + s4[2] + s4[3];
    return r;
}

// ---------- convert fp32 [b][c][p] -> bf16 xT[which][b][p][c] + fused norm partials ----------
// v4 (kept): at the measured pattern-level wall (~2.25 TB/s across 4 structural variants).
__global__ __launch_bounds__(256) void convert_kernel(const float* __restrict__ x1,
                                                      const float* __restrict__ x2,
                                                      ushort* __restrict__ xT,
                                                      float* __restrict__ normp) {
    int z = blockIdx.y;
    int which = z >> 6, b = z & 63;
    int half = blockIdx.x & 1;
    int pt = blockIdx.x >> 1;          // 0..8
    int p0 = pt * 64, c0 = half * 384;
    const float* X = (which ? x2 : x1) + ((size_t)b * C + c0) * HW + p0;

    __shared__ ushort tile[64][392];   // [p][c], 784B row stride
    __shared__ float nlds[64][4];

    int t = threadIdx.x;
    int pq = t & 15, cq = t >> 4;      // p-quad (16), c-quad (16)
    int w = t >> 6;

    float ss[4] = {0.f, 0.f, 0.f, 0.f};

#pragma unroll
    for (int pass = 0; pass < 6; ++pass) {
        floatx4 v[4];
#pragma unroll
        for (int i = 0; i < 4; ++i)
            v[i] = *(const floatx4*)(X + (size_t)(pass * 64 + 4 * cq + i) * HW + 4 * pq);
#pragma unroll
        for (int j = 0; j < 4; ++j) {
            ushort u0 = f2bf(v[0][j]), u1 = f2bf(v[1][j]);
            ushort u2 = f2bf(v[2][j]), u3 = f2bf(v[3][j]);
            ushort4 uu; uu.x = u0; uu.y = u1; uu.z = u2; uu.w = u3;
            *(ushort4*)&tile[4 * pq + j][pass * 64 + 4 * cq] = uu;
            float r0 = bf2f(u0), r1 = bf2f(u1), r2 = bf2f(u2), r3 = bf2f(u3);
            ss[j] = fmaf(r0, r0, ss[j]); ss[j] = fmaf(r1, r1, ss[j]);
            ss[j] = fmaf(r2, r2, ss[j]); ss[j] = fmaf(r3, r3, ss[j]);
        }
    }
#pragma unroll
    for (int j = 0; j < 4; ++j) {
        ss[j] += __shfl_xor(ss[j], 16, 64);
        ss[j] += __shfl_xor(ss[j], 32, 64);
    }
    if ((t & 63) < 16) {
#pragma unroll
        for (int j = 0; j < 4; ++j) nlds[4 * pq + j][w] = ss[j];
    }
    __syncthreads();

    ushort* dst = xT + (((size_t)which * B + b) * HW + p0) * C + c0;
    const char* tb = (const char*)tile;
#pragma unroll
    for (int step = 0; step < 12; ++step) {
        int ib = (step * 256 + t) * 16;
        int p = ib / 768, cb = ib % 768;
        short8 vv = *(const short8*)(tb + (size_t)p * 784 + cb);
        *(short8*)(dst + (size_t)p * C + (cb >> 1)) = vv;
    }
    if (t < 64) {
        float nv = nlds[t][0] + nlds[t][1] + nlds[t][2] + nlds[t][3];
        normp[((size_t)half * 128 + which * 64 + b) * HW + p0 + t] = nv;
    }
}

// ---------- deep-pipelined MFMA K-loop ----------
// v2: granule = 32 c-columns; 4 LDS buffers x 16KB (A 8K + B 8K); issue 3 granules ahead;
// ONE barrier per granule; counted vmcnt(8) steady state (12 loads/wave in flight).
// Safety: buffer (h+3)&3 == (h-1)&3, whose readers all passed barrier h (compute h-1 is
// between barriers h-1 and h); own-wave WAW guarded by own vmcnt at iter h-1.
template<int NG>
__device__ __forceinline__ void gemm_pp(const ushort* const (&gA)[2], const ushort* const (&gB)[2],
                                        char* pool, int w,
                                        const int (&offA)[4], const int (&offB)[4],
                                        floatx4 (&acc)[4][4]) {
    auto issue = [&](int h) {
        char* buf = pool + (h & 3) * 16384;
#pragma unroll
        for (int n = 0; n < 2; ++n) {
            __builtin_amdgcn_global_load_lds(
                (const __attribute__((address_space(1))) void*)(gA[n] + h * 32),
                (__attribute__((address_space(3))) void*)(buf + w * 2048 + n * 1024), 16, 0, 0);
            __builtin_amdgcn_global_load_lds(
                (const __attribute__((address_space(1))) void*)(gB[n] + h * 32),
                (__attribute__((address_space(3))) void*)(buf + 8192 + w * 2048 + n * 1024), 16, 0, 0);
        }
    };
    issue(0); issue(1); issue(2);
    for (int h = 0; h < NG; ++h) {
        if (h < NG - 2)      asm volatile("s_waitcnt vmcnt(8)" ::: "memory");
        else if (h == NG - 2) asm volatile("s_waitcnt vmcnt(4)" ::: "memory");
        else                  asm volatile("s_waitcnt vmcnt(0)" ::: "memory");
        __builtin_amdgcn_s_barrier();
        if (h + 3 < NG) issue(h + 3);
        __builtin_amdgcn_sched_barrier(0);
        const char* buf = pool + (h & 3) * 16384;
        short8 a[4], bb[4];
#pragma unroll
        for (int i = 0; i < 4; ++i) a[i] = *(const short8*)(buf + offA[i]);
#pragma unroll
        for (int j = 0; j < 4; ++j) bb[j] = *(const short8*)(buf + 8192 + offB[j]);
#pragma unroll
        for (int i = 0; i < 4; ++i)
#pragma unroll
            for (int j = 0; j < 4; ++j)
                acc[i][j] = __builtin_amdgcn_mfma_f32_16x16x32_bf16(a[i], bb[j], acc[i][j], 0, 0, 0);
    }
    // loop exit: vmcnt==0 for this wave (h=NG-1 drained)
}

// ---------- cdist Gram via MFMA, 128x128 tile, XCD-swizzled 1-D grid ----------
__global__ __launch_bounds__(256) void cdist_mfma(const ushort* __restrict__ xT,
                                                  const float* __restrict__ normp,
                                                  ull* __restrict__ nn1,
                                                  ull* __restrict__ nn2) {
    int id = blockIdx.x;
    int xcd = id & 7, slot = id >> 3;
    int b = xcd + 8 * (slot / 25);      // all 25 tiles of a batch share one XCD slot
    int t = slot % 25;
    int qt = t % 5, pt = t / 5;

    const ushort* X1 = xT + (size_t)b * HW * C;
    const ushort* X2 = xT + (size_t)(B + b) * HW * C;

    __shared__ ull pool[8192];          // 65536 B: 4 x (A 8K + B 8K); red overlays
    char* poolc = (char*)pool;

    int tid = threadIdx.x;
    int w = tid >> 6, l = tid & 63;
    int quad = l >> 4, col = l & 15;
    int lrow = l >> 2, pos = l & 3;

    const ushort* gA[2]; const ushort* gB[2];
#pragma unroll
    for (int n = 0; n < 2; ++n) {
        int sm = w * 32 + n * 16 + lrow;            // LDS row 0..127
        int cdat = pos ^ ((sm >> 1) & 3);
        int p = pt * 128 + sm; if (p >= HW) p = HW - 1;
        int q = qt * 128 + sm; if (q >= HW) q = HW - 1;
        gA[n] = X1 + (size_t)p * C + cdat * 8;
        gB[n] = X2 + (size_t)q * C + cdat * 8;
    }

    int offA[4], offB[4];
#pragma unroll
    for (int i = 0; i < 4; ++i) {
        int m_loc = (w >> 1) * 64 + i * 16 + col;
        offA[i] = m_loc * 64 + ((quad ^ ((m_loc >> 1) & 3)) * 16);
        int n_loc = (w & 1) * 64 + i * 16 + col;
        offB[i] = n_loc * 64 + ((quad ^ ((n_loc >> 1) & 3)) * 16);
    }

    floatx4 zero = {0.f, 0.f, 0.f, 0.f};
    floatx4 acc[4][4];
#pragma unroll
    for (int i = 0; i < 4; ++i)
#pragma unroll
        for (int j = 0; j < 4; ++j) acc[i][j] = zero;

    gemm_pp<24>(gA, gB, poolc, w, offA, offB, acc);

    // norms: sum of the two c-half partials
    const float* n1a = normp + (size_t)b * HW;
    const float* n1b = normp + (size_t)(128 + b) * HW;
    const float* n2a = normp + (size_t)(64 + b) * HW;
    const float* n2b = normp + (size_t)(192 + b) * HW;
    float n1v[4][4]; bool vp[4][4];
    float n2v[4];    bool vq[4];
#pragma unroll
    for (int i = 0; i < 4; ++i)
#pragma unroll
        for (int r = 0; r < 4; ++r) {
            int p = pt * 128 + (w >> 1) * 64 + i * 16 + quad * 4 + r;
            vp[i][r] = (p < HW);
            int pc = p < HW ? p : (HW - 1);
            n1v[i][r] = n1a[pc] + n1b[pc];
        }
#pragma unroll
    for (int j = 0; j < 4; ++j) {
        int q = qt * 128 + (w & 1) * 64 + j * 16 + col;
        vq[j] = (q < HW);
        int qc = q < HW ? q : (HW - 1);
        n2v[j] = n2a[qc] + n2b[qc];
    }

    __syncthreads();
    typedef ull row33[33];
    row33* red = (row33*)pool;

    // pass 1: per-p min over q
#pragma unroll
    for (int i = 0; i < 4; ++i)
#pragma unroll
        for (int r = 0; r < 4; ++r) {
            int p_loc = (w >> 1) * 64 + i * 16 + quad * 4 + r;
            ull best = ~0ull;
#pragma unroll
            for (int j = 0; j < 4; ++j) {
                if (!vq[j]) continue;
                float d2 = fmaxf(n1v[i][r] + n2v[j] - 2.0f * acc[i][j][r], 0.0f);
                unsigned q_glob = qt * 128 + (w & 1) * 64 + j * 16 + col;
                best = umin64(best, ((ull)__float_as_uint(d2) << 32) | q_glob);
            }
            red[p_loc][(w & 1) * 16 + col] = best;
        }
    __syncthreads();
    if (tid < 128) {
        int p_glob = pt * 128 + tid;
        ull m = ~0ull;
#pragma unroll
        for (int x = 0; x < 32; ++x) m = umin64(m, red[tid][x]);
        if (p_glob < HW) atomicMin(&nn1[(size_t)b * HW + p_glob], m);
    }
    __syncthreads();
    // pass 2: per-q min over p
#pragma unroll
    for (int j = 0; j < 4; ++j) {
        int q_loc = (w & 1) * 64 + j * 16 + col;
        ull best = ~0ull;
#pragma unroll
        for (int i = 0; i < 4; ++i)
#pragma unroll
            for (int r = 0; r < 4; ++r) {
                if (!vp[i][r]) continue;
                float d2 = fmaxf(n1v[i][r] + n2v[j] - 2.0f * acc[i][j][r], 0.0f);
                unsigned p_glob = pt * 128 + (w >> 1) * 64 + i * 16 + quad * 4 + r;
                best = umin64(best, ((ull)__float_as_uint(d2) << 32) | p_glob);
            }
        red[q_loc][(w >> 1) * 4 + quad] = best;
    }
    __syncthreads();
    if (tid < 128) {
        int q_glob = qt * 128 + tid;
        ull m = ~0ull;
#pragma unroll
        for (int x = 0; x < 8; ++x) m = umin64(m, red[tid][x]);
        if (q_glob < HW) atomicMin(&nn2[(size_t)b * HW + q_glob], m);
    }
}

// ---------- top-k: one wave per (b,dir), keys in registers ----------
__global__ __launch_bounds__(64) void select_topk_wave(const ull* __restrict__ nn1,
                                                       const ull* __restrict__ nn2,
                                                       int* __restrict__ sel_p,
                                                       int* __restrict__ sel_q) {
    int b = blockIdx.x, dir = blockIdx.y;
    const ull* nn = dir ? nn2 : nn1;
    int lane = threadIdx.x;
    ull key[9]; uint qv[9];
#pragma unroll
    for (int r = 0; r < 9; ++r) {
        int p = r * 64 + lane;
        ull e = nn[(size_t)b * HW + p];
        key[r] = (e & 0xFFFFFFFF00000000ull) | (unsigned)p;
        qv[r] = (uint)(e & 0xFFFFFFFFu);
    }
    int* sp = sel_p + (dir * B + b) * K;
    int* sq = sel_q + (dir * B + b) * K;
    for (int it = 0; it < K; ++it) {
        ull m = key[0];
#pragma unroll
        for (int r = 1; r < 9; ++r) m = umin64(m, key[r]);
#pragma unroll
        for (int off = 32; off > 0; off >>= 1) m = umin64(m, __shfl_xor(m, off, 64));
#pragma unroll
        for (int r = 0; r < 9; ++r) {
            if (key[r] == m) {
                sp[it] = (int)(uint)(m & 0xFFFFFFFFu);
                sq[it] = (int)qv[r];
                key[r] = ~0ull;
            }
        }
    }
}

// ---------- gather into XgT[s][c][i], i = j*64 + b (coalesced writes) ----------
__global__ __launch_bounds__(256) void gather_jmajor(const ushort* __restrict__ xT,
                                                     const int* __restrict__ sel_p,
                                                     const int* __restrict__ sel_q,
                                                     ushort* __restrict__ XgT) {
    int j = blockIdx.x, s = blockIdx.y;
    int dir = s >> 1;
    int whichsrc = (s == 1 || s == 2) ? 1 : 0;
    const int* sel = (s & 1) ? sel_q : sel_p;
    __shared__ int sidx[64];
    __shared__ uint buf[64][33];
    int tid = threadIdx.x;
    if (tid < 64) sidx[tid] = sel[(dir * B + tid) * K + j];
    __syncthreads();
    int rb = tid >> 2, u = tid & 3;
    const ushort* srow = xT + (((size_t)whichsrc * B + rb) * HW + sidx[rb]) * C;
    int wv = tid >> 6, lb = tid & 63;
    ushort* obase = XgT + (size_t)s * C * NLOC + (size_t)j * 64 + lb;
    for (int ch = 0; ch < 12; ++ch) {
        __syncthreads();
        uint4 v0 = *(const uint4*)(srow + ch * 64 + u * 8);
        uint4 v1 = *(const uint4*)(srow + ch * 64 + (u + 4) * 8);
        buf[rb][u * 4 + 0] = v0.x; buf[rb][u * 4 + 1] = v0.y;
        buf[rb][u * 4 + 2] = v0.z; buf[rb][u * 4 + 3] = v0.w;
        buf[rb][(u + 4) * 4 + 0] = v1.x; buf[rb][(u + 4) * 4 + 1] = v1.y;
        buf[rb][(u + 4) * 4 + 2] = v1.z; buf[rb][(u + 4) * 4 + 3] = v1.w;
        __syncthreads();
#pragma unroll
        for (int st = 0; st < 16; ++st) {
            int cl = wv + st * 4;
            uint uv = buf[lb][cl >> 1];
            ushort val = (cl & 1) ? (ushort)(uv >> 16) : (ushort)(uv & 0xffffu);
            obase[(size_t)(ch * 64 + cl) * NLOC] = val;
        }
    }
}

// ---------- Mp[mat][split] = partial X^T X via MFMA, 128x128 tile, split-K=5 ----------
__global__ __launch_bounds__(256) void ata_mfma(const ushort* __restrict__ XgT,
                                                float* __restrict__ Mp) {
    int bx = blockIdx.x;                 // 0..35
    int mat = blockIdx.y, split = blockIdx.z;
    int rt = bx / 6, ct = bx % 6;
    const ushort* X = XgT + (size_t)mat * C * NLOC;

    __shared__ ull pool[8192];           // 65536 B: 4 x (A 8K + B 8K)
    char* poolc = (char*)pool;

    int tid = threadIdx.x;
    int w = tid >> 6, l = tid & 63;
    int quad = l >> 4, col = l & 15;
    int lrow = l >> 2, pos = l & 3;

    const ushort* gA[2]; const ushort* gB[2];
#pragma unroll
    for (int n = 0; n < 2; ++n) {
        int sm = w * 32 + n * 16 + lrow;
        int cdat = pos ^ ((sm >> 1) & 3);
        gA[n] = X + (size_t)(rt * 128 + sm) * NLOC + split * 640 + cdat * 8;
        gB[n] = X + (size_t)(ct * 128 + sm) * NLOC + split * 640 + cdat * 8;
    }

    int offA[4], offB[4];
#pragma unroll
    for (int i = 0; i < 4; ++i) {
        int m_loc = (w >> 1) * 64 + i * 16 + col;
        offA[i] = m_loc * 64 + ((quad ^ ((m_loc >> 1) & 3)) * 16);
        int n_loc = (w & 1) * 64 + i * 16 + col;
        offB[i] = n_loc * 64 + ((quad ^ ((n_loc >> 1) & 3)) * 16);
    }

    floatx4 zero = {0.f, 0.f, 0.f, 0.f};
    floatx4 acc[4][4];
#pragma unroll
    for (int i = 0; i < 4; ++i)
#pragma unroll
        for (int j = 0; j < 4; ++j) acc[i][j] = zero;

    gemm_pp<20>(gA, gB, poolc, w, offA, offB, acc);

    float* Mo = Mp + (size_t)(mat * 5 + split) * C * C;
#pragma unroll
    for (int i = 0; i < 4; ++i)
#pragma unroll
        for (int j = 0; j < 4; ++j)
#pragma unroll
            for (int r = 0; r < 4; ++r) {
                int row = rt * 128 + (w >> 1) * 64 + i * 16 + quad * 4 + r;
                int cc  = ct * 128 + (w & 1) * 64 + j * 16 + col;
                Mo[(size_t)row * C + cc] = acc[i][j][r];
            }
}

// ---------- fp32 X^T X for pooled mats (4,5), n=64 ----------
__global__ __launch_bounds__(256) void ata_pooled(const float* __restrict__ p1,
                                                  const float* __restrict__ p2,
                                                  float* __restrict__ M) {
    int mat = 4 + blockIdx.z;
    const float* X = (mat == 4) ? p1 : p2;
    int n = B;
    float* Mo = M + (size_t)mat * C * C;
    int ct = blockIdx.x, rt = blockIdx.y;

    __shared__ float As[16][64];
    __shared__ float Bs[16][64];
    int tid = threadIdx.x;
    int tx = tid & 15, ty = tid >> 4;
    int lr = tid >> 4, lc = (tid & 15) * 4;

    float acc[4][4] = {};
    for (int k0 = 0; k0 < n; k0 += 16) {
        float4 av = *(const float4*)&X[(size_t)(k0 + lr) * C + rt * 64 + lc];
        float4 bv = *(const float4*)&X[(size_t)(k0 + lr) * C + ct * 64 + lc];
        __syncthreads();
        *(float4*)&As[lr][lc] = av;
        *(float4*)&Bs[lr][lc] = bv;
        __syncthreads();
#pragma unroll
        for (int kk = 0; kk < 16; ++kk) {
            float4 af = *(const float4*)&As[kk][ty * 4];
            float4 bf = *(const float4*)&Bs[kk][tx * 4];
            float a[4] = {af.x, af.y, af.z, af.w};
            float bb[4] = {bf.x, bf.y, bf.z, bf.w};
#pragma unroll
            for (int i = 0; i < 4; ++i)
#pragma unroll
                for (int j = 0; j < 4; ++j)
                    acc[i][j] = fmaf(a[i], bb[j], acc[i][j]);
        }
    }
#pragma unroll
    for (int i = 0; i < 4; ++i) {
        float4 o = {acc[i][0], acc[i][1], acc[i][2], acc[i][3]};
        *(float4*)&Mo[(size_t)(rt * 64 + ty * 4 + i) * C + ct * 64 + tx * 4] = o;
    }
}

// ---------- colsum for mats 0..3 from XgT (no atomics) ----------
__global__ __launch_bounds__(256) void colsum4_kernel(const ushort* __restrict__ XgT,
                                                      float* __restrict__ colsum) {
    int mat = blockIdx.y, cb = blockIdx.x * 4;
    int r = threadIdx.x >> 6, lane = threadIdx.x & 63;
    const ushort* row = XgT + ((size_t)mat * C + cb + r) * NLOC;
    float s = 0.f;
    for (int i = lane; i < NLOC; i += 64) s += bf2f(row[i]);
    for (int off = 32; off > 0; off >>= 1) s += __shfl_down(s, off, 64);
    if (lane == 0) colsum[mat * C + cb + r] = s;
}

// ---------- colsum pooled (no atomics) ----------
__global__ __launch_bounds__(256) void colsum_pooled(const float* __restrict__ p1,
                                                     const float* __restrict__ p2,
                                                     float* __restrict__ colsum) {
    int mat = 4 + blockIdx.y;
    const float* X = (mat == 4) ? p1 : p2;
    int c = blockIdx.x * 256 + threadIdx.x;
    float s = 0.f;
    for (int r = 0; r < B; ++r) s += X[(size_t)r * C + c];
    colsum[mat * C + c] = s;
}

// ---------- std term (reads Mp splits directly for mats 0-3; bit-identical to reduce_mp path) ----------
__global__ __launch_bounds__(256) void std_kernel(const float* __restrict__ Mp,
                                                  const float* __restrict__ M,
                                                  const float* __restrict__ colsum,
                                                  float* __restrict__ slots) {
    int mat = blockIdx.y;
    float n = (mat < 4) ? (float)NLOC : (float)B;
    int c = blockIdx.x * 256 + threadIdx.x;
    float r = 0.f;
    if (c < C) {
        float mcc;
        if (mat < 4) {
            mcc = 0.f;
#pragma unroll
            for (int s = 0; s < 5; ++s)
                mcc += Mp[(size_t)(mat * 5 + s) * C * C + (size_t)c * C + c];
        } else {
            mcc = M[(size_t)mat * C * C + (size_t)c * C + c];
        }
        float cs = colsum[mat * C + c];
        float var = (mcc - cs * cs / n) / (n - 1.0f);
        float sd = sqrtf(var + 1e-5f);
        float g = 1.0f - sd;
        r = g > 0.f ? g : 0.f;
    }
    __shared__ float s4[4];
    float t = blk_reduce_sum(r, s4);
    if (threadIdx.x == 0) atomicAdd(&slots[SLOT_STD + mat], t);
}

// ---------- cov term (reads Mp splits directly for mats 0-3; sum in s-order = bit-identical) ----------
__global__ __launch_bounds__(256) void cov_kernel(const float* __restrict__ Mp,
                                                  const float* __restrict__ M,
                                                  const float* __restrict__ colsum,
                                                  float* __restrict__ slots) {
    int mat = blockIdx.y;
    float n = (mat < 4) ? (float)NLOC : (float)B;
    float invn1 = 1.0f / (n - 1.0f);
    __shared__ float cs_s[C];
    for (int c = threadIdx.x; c < C; c += 256) cs_s[c] = colsum[mat * C + c];
    __syncthreads();
    float s = 0.f;
    int r0 = blockIdx.x * 16;
    for (int r = 0; r < 16; ++r) {
        int row = r0 + r;
        float csr = cs_s[row] / n;
        if (mat < 4) {
            const float* Mr0 = Mp + (size_t)(mat * 5 + 0) * C * C + (size_t)row * C;
            const float* Mr1 = Mp + (size_t)(mat * 5 + 1) * C * C + (size_t)row * C;
            const float* Mr2 = Mp + (size_t)(mat * 5 + 2) * C * C + (size_t)row * C;
            const float* Mr3 = Mp + (size_t)(mat * 5 + 3) * C * C + (size_t)row * C;
            const float* Mr4 = Mp + (size_t)(mat * 5 + 4) * C * C + (size_t)row * C;
            for (int c = threadIdx.x; c < C; c += 256) {
                float v = Mr0[c];
                v += Mr1[c]; v += Mr2[c]; v += Mr3[c]; v += Mr4[c];
                float cv = (v - csr * cs_s[c]) * invn1;
                if (c != row) s = fmaf(cv, cv, s);
            }
        } else {
            const float* Mr = M + (size_t)mat * C * C + (size_t)row * C;
            for (int c = threadIdx.x; c < C; c += 256) {
                float cv = (Mr[c] - csr * cs_s[c]) * invn1;
                if (c != row) s = fmaf(cv, cv, s);
            }
        }
    }
    __shared__ float s4[4];
    float t = blk_reduce_sum(s, s4);
    if (threadIdx.x == 0) atomicAdd(&slots[SLOT_COV + mat], t);
}

// ---------- invariance terms ----------
__global__ __launch_bounds__(256) void inv_global_kernel(const float* __restrict__ p1,
                                                         const float* __restrict__ p2,
                                                         float* __restrict__ slots) {
    int idx = blockIdx.x * 256 + threadIdx.x;
    int stride = gridDim.x * 256;
    float s = 0.f;
    for (int i = idx; i < B * C; i += stride) {
        float d = p1[i] - p2[i];
        s = fmaf(d, d, s);
    }
    __shared__ float s4[4];
    float t = blk_reduce_sum(s, s4);
    if (threadIdx.x == 0) atomicAdd(&slots[SLOT_INVG], t);
}

__global__ __launch_bounds__(256) void inv_local2(const ushort* __restrict__ XgT,
                                                  float* __restrict__ slots) {
    int pair = blockIdx.y;
    const uint* A4 = (const uint*)(XgT + (size_t)(2 * pair) * C * NLOC);
    const uint* B4 = (const uint*)(XgT + (size_t)(2 * pair + 1) * C * NLOC);
    int idx = blockIdx.x * 256 + threadIdx.x;
    int stride = gridDim.x * 256;
    int n = C * NLOC / 2;
    float s = 0.f;
    for (int i = idx; i < n; i += stride) {
        uint ua = A4[i], ub = B4[i];
        float d0 = bf2f_lo(ua) - bf2f_lo(ub);
        float d1 = bf2f_hi(ua) - bf2f_hi(ub);
        s = fmaf(d0, d0, s);
        s = fmaf(d1, d1, s);
    }
    __shared__ float s4[4];
    float t = blk_reduce_sum(s, s4);
    if (threadIdx.x == 0) atomicAdd(&slots[(pair == 0) ? SLOT_INV1 : SLOT_INV2], t);
}

// ---------- final combine ----------
__global__ void final_kernel(const float* __restrict__ slots, float* __restrict__ out) {
    float std_t[6], cov_t[6];
    for (int m = 0; m < 6; ++m) {
        std_t[m] = slots[SLOT_STD + m] / (float)C * 0.5f;
        cov_t[m] = slots[SLOT_COV + m] / (float)C;
    }
    float inv_g = slots[SLOT_INVG] / (float)(B * C);
    float global_loss = 25.0f * inv_g + 25.0f * (std_t[4] + std_t[5]) + (cov_t[4] + cov_t[5]);
    float inv1 = 25.0f * slots[SLOT_INV1] / (float)(NLOC * C);
    float inv2 = 25.0f * slots[SLOT_INV2] / (float)(NLOC * C);
    float var1 = 25.0f * (std_t[0] + std_t[1]);
    float var2 = 25.0f * (std_t[2] + std_t[3]);
    float cov1 = cov_t[0] + cov_t[1];
    float cov2 = cov_t[2] + cov_t[3];
    float local_loss = (inv1 + inv2) * 0.5f + (var1 + var2) * 0.5f + (cov1 + cov2) * 0.5f;
    out[0] = 0.5f * global_loss + 0.5f * local_loss;
}

extern "C" void kernel_launch(void* const* d_in, const int* in_sizes, int n_in,
                              void* d_out, int out_size, void* d_ws, size_t ws_size,
                              hipStream_t stream) {
    const float* spatial_1 = (const float*)d_in[0];
    const float* pooled_1  = (const float*)d_in[1];
    const float* spatial_2 = (const float*)d_in[2];
    const float* pooled_2  = (const float*)d_in[3];
    float* out = (float*)d_out;

    char* ws = (char*)d_ws;
    float*  slots  = (float*)(ws + OFF_SLOTS);
    float*  colsum = (float*)(ws + OFF_COLSUM);
    ull*    nn1    = (ull*)(ws + OFF_NN1);
    ull*    nn2    = (ull*)(ws + OFF_NN2);
    int*    sel_p  = (int*)(ws + OFF_SELP);
    int*    sel_q  = (int*)(ws + OFF_SELQ);
    ushort* xT     = (ushort*)(ws + OFF_XT);
    float*  Mp     = (float*)(ws + OFF_MP);   // overlays xT (dead after gather)
    ushort* XgT    = (ushort*)(ws + OFF_XGT);
    float*  M      = (float*)(ws + OFF_M);
    float*  normp  = (float*)(ws + OFF_M);    // [2 halves][2*64][576] overlay in mats 0-3 region

    hipMemsetAsync(ws, 0, OFF_NN1, stream);                          // slots + colsum
    hipMemsetAsync(ws + OFF_NN1, 0xFF, OFF_SELP - OFF_NN1, stream);  // nn keys

    convert_kernel<<<dim3(18, 128), 256, 0, stream>>>(spatial_1, spatial_2, xT, normp);
    cdist_mfma<<<1600, 256, 0, stream>>>(xT, normp, nn1, nn2);
    select_topk_wave<<<dim3(B, 2), 64, 0, stream>>>(nn1, nn2, sel_p, sel_q);
    gather_jmajor<<<dim3(K, 4), 256, 0, stream>>>(xT, sel_p, sel_q, XgT);
    ata_mfma<<<dim3(36, 4, 5), 256, 0, stream>>>(XgT, Mp);
    ata_pooled<<<dim3(12, 12, 2), 256, 0, stream>>>(pooled_1, pooled_2, M);
    colsum4_kernel<<<dim3(192, 4), 256, 0, stream>>>(XgT, colsum);
    colsum_pooled<<<dim3(3, 2), 256, 0, stream>>>(pooled_1, pooled_2, colsum);
    std_kernel<<<dim3(3, 6), 256, 0, stream>>>(Mp, M, colsum, slots);
    cov_kernel<<<dim3(48, 6), 256, 0, stream>>>(Mp, M, colsum, slots);
    inv_global_kernel<<<dim3(96), 256, 0, stream>>>(pooled_1, pooled_2, slots);
    inv_local2<<<dim3(300, 2), 256, 0, stream>>>(XgT, slots);
    final_kernel<<<1, 1, 0, stream>>>(slots, out);
}

// Round 5
// 448.142 us; speedup vs baseline: 1.0783x; 1.0493x over previous
//
#include <hip/hip_runtime.h>
#include <stdint.h>

typedef unsigned long long ull;
typedef unsigned int uint;
typedef unsigned short ushort;

typedef __attribute__((ext_vector_type(8))) short short8;
typedef __attribute__((ext_vector_type(4))) float floatx4;

#define B   64
#define C   768
#define HW  576
#define K   50
#define NLOC (B*K)          // 3200

// ---- workspace layout (bytes) ----
#define OFF_SLOTS   0            // 64 floats
#define OFF_COLSUM  256          // 6*768*4 = 18432
#define OFF_NN1     18688        // 64*576*8 = 294912
#define OFF_NN2     313600       // 294912
#define OFF_SELP    608512       // 2*64*50*4 = 25600
#define OFF_SELQ    634112       // 25600
#define OFF_XT      954624       // 2*64*576*768*2 = 113246208  (dead after gather -> reused as Mp)
#define OFF_MP      OFF_XT       // 4 mats * 5 splits * 768*768*4 = 47185920 (fits in XT region)
#define OFF_XGT     114200832    // 4*768*3200*2 = 19660800
#define OFF_M       133861632    // 6*768*768*4 (mats 4,5 used; mats 0-3 region = normp overlay)
// total 148017408

#define SLOT_INVG 0
#define SLOT_STD  1   // +mat (0..5)
#define SLOT_COV  7   // +mat (0..5)
#define SLOT_INV1 13
#define SLOT_INV2 14

__device__ __forceinline__ ull umin64(ull a, ull b) { return a < b ? a : b; }

__device__ __forceinline__ float bf2f_lo(uint u) { return __uint_as_float(u << 16); }
__device__ __forceinline__ float bf2f_hi(uint u) { return __uint_as_float(u & 0xffff0000u); }
__device__ __forceinline__ float bf2f(ushort u) { return __uint_as_float(((uint)u) << 16); }

__device__ __forceinline__ ushort f2bf(float f) {
    uint u = __float_as_uint(f);
    uint r = (u + 0x7fffu + ((u >> 16) & 1u)) >> 16;   // RNE
    return (ushort)r;
}

__device__ __forceinline__ float blk_reduce_sum(float v, float* s4) {
    for (int off = 32; off > 0; off >>= 1) v += __shfl_down(v, off, 64);
    int lane = threadIdx.x & 63, w = threadIdx.x >> 6;
    if (lane == 0) s4[w] = v;
    __syncthreads();
    float r = 0.f;
    if (threadIdx.x == 0) r = s4[0] + s4[1] + s4[2] + s4[3];
    return r;
}

// ---------- convert fp32 [b][c][p] -> bf16 xT[which][b][p][c] + fused norm partials ----------
// (kept: measured pattern-level wall ~2.25 TB/s across 4 structural variants)
__global__ __launch_bounds__(256) void convert_kernel(const float* __restrict__ x1,
                                                      const float* __restrict__ x2,
                                                      ushort* __restrict__ xT,
                                                      float* __restrict__ normp) {
    int z = blockIdx.y;
    int which = z >> 6, b = z & 63;
    int half = blockIdx.x & 1;
    int pt = blockIdx.x >> 1;          // 0..8
    int p0 = pt * 64, c0 = half * 384;
    const float* X = (which ? x2 : x1) + ((size_t)b * C + c0) * HW + p0;

    __shared__ ushort tile[64][392];   // [p][c], 784B row stride
    __shared__ float nlds[64][4];

    int t = threadIdx.x;
    int pq = t & 15, cq = t >> 4;      // p-quad (16), c-quad (16)
    int w = t >> 6;

    float ss[4] = {0.f, 0.f, 0.f, 0.f};

#pragma unroll
    for (int pass = 0; pass < 6; ++pass) {
        floatx4 v[4];
#pragma unroll
        for (int i = 0; i < 4; ++i)
            v[i] = *(const floatx4*)(X + (size_t)(pass * 64 + 4 * cq + i) * HW + 4 * pq);
#pragma unroll
        for (int j = 0; j < 4; ++j) {
            ushort u0 = f2bf(v[0][j]), u1 = f2bf(v[1][j]);
            ushort u2 = f2bf(v[2][j]), u3 = f2bf(v[3][j]);
            ushort4 uu; uu.x = u0; uu.y = u1; uu.z = u2; uu.w = u3;
            *(ushort4*)&tile[4 * pq + j][pass * 64 + 4 * cq] = uu;
            float r0 = bf2f(u0), r1 = bf2f(u1), r2 = bf2f(u2), r3 = bf2f(u3);
            ss[j] = fmaf(r0, r0, ss[j]); ss[j] = fmaf(r1, r1, ss[j]);
            ss[j] = fmaf(r2, r2, ss[j]); ss[j] = fmaf(r3, r3, ss[j]);
        }
    }
#pragma unroll
    for (int j = 0; j < 4; ++j) {
        ss[j] += __shfl_xor(ss[j], 16, 64);
        ss[j] += __shfl_xor(ss[j], 32, 64);
    }
    if ((t & 63) < 16) {
#pragma unroll
        for (int j = 0; j < 4; ++j) nlds[4 * pq + j][w] = ss[j];
    }
    __syncthreads();

    ushort* dst = xT + (((size_t)which * B + b) * HW + p0) * C + c0;
    const char* tb = (const char*)tile;
#pragma unroll
    for (int step = 0; step < 12; ++step) {
        int ib = (step * 256 + t) * 16;
        int p = ib / 768, cb = ib % 768;
        short8 vv = *(const short8*)(tb + (size_t)p * 784 + cb);
        *(short8*)(dst + (size_t)p * C + (cb >> 1)) = vv;
    }
    if (t < 64) {
        float nv = nlds[t][0] + nlds[t][1] + nlds[t][2] + nlds[t][3];
        normp[((size_t)half * 128 + which * 64 + b) * HW + p0 + t] = nv;
    }
}

// ---------- 64x128-tile, 4-wave, 4-deep pipelined MFMA K-loop ----------
// Granule = 32 c. LDS: 4 bufs x 12KB (A 4KB + B 8KB). Lookahead 3, vmcnt(6) steady.
// 3 loads/wave/granule (A chunk w; B chunks w, w+4). ~110 regs/wave -> <=128 bucket
// -> 3 blocks/CU (3 independent barrier groups) vs previous 2x8-wave.
template<int NG>
__device__ __forceinline__ void gemm_pp64(const ushort* gA, const ushort* gB0, const ushort* gB1,
                                          char* pool, int w,
                                          const int (&offA)[4], const int (&offB)[2],
                                          floatx4 (&acc)[4][2]) {
    auto issue = [&](int h) {
        char* buf = pool + (h & 3) * 12288;
        __builtin_amdgcn_global_load_lds(
            (const __attribute__((address_space(1))) void*)(gA + h * 32),
            (__attribute__((address_space(3))) void*)(buf + w * 1024), 16, 0, 0);
        __builtin_amdgcn_global_load_lds(
            (const __attribute__((address_space(1))) void*)(gB0 + h * 32),
            (__attribute__((address_space(3))) void*)(buf + 4096 + w * 1024), 16, 0, 0);
        __builtin_amdgcn_global_load_lds(
            (const __attribute__((address_space(1))) void*)(gB1 + h * 32),
            (__attribute__((address_space(3))) void*)(buf + 4096 + (4 + w) * 1024), 16, 0, 0);
    };
    issue(0); issue(1); issue(2);
    for (int h = 0; h < NG; ++h) {
        if (h < NG - 2)       asm volatile("s_waitcnt vmcnt(6)" ::: "memory");
        else if (h == NG - 2) asm volatile("s_waitcnt vmcnt(3)" ::: "memory");
        else                  asm volatile("s_waitcnt vmcnt(0)" ::: "memory");
        __builtin_amdgcn_s_barrier();
        if (h + 3 < NG) issue(h + 3);
        __builtin_amdgcn_sched_barrier(0);
        const char* buf = pool + (h & 3) * 12288;
        short8 a[4], bb[2];
#pragma unroll
        for (int i = 0; i < 4; ++i) a[i] = *(const short8*)(buf + offA[i]);
#pragma unroll
        for (int j = 0; j < 2; ++j) bb[j] = *(const short8*)(buf + offB[j]);
#pragma unroll
        for (int i = 0; i < 4; ++i)
#pragma unroll
            for (int j = 0; j < 2; ++j)
                acc[i][j] = __builtin_amdgcn_mfma_f32_16x16x32_bf16(a[i], bb[j], acc[i][j], 0, 0, 0);
    }
}

// ---------- cdist Gram via MFMA, 64x128 tile, XCD-swizzled 1-D grid ----------
__global__ __launch_bounds__(256, 3) void cdist_mfma(const ushort* __restrict__ xT,
                                                     const float* __restrict__ normp,
                                                     ull* __restrict__ nn1,
                                                     ull* __restrict__ nn2) {
    int id = blockIdx.x;
    int xcd = id & 7, slot = id >> 3;
    int b = xcd + 8 * (slot / 45);      // all 45 tiles of a batch share one XCD slot
    int t = slot % 45;
    int qt = t % 5, pt = t / 5;         // pt 0..8 (exact 9x64=576), qt 0..4 (128-tiles, last padded)

    const ushort* X1 = xT + (size_t)b * HW * C;
    const ushort* X2 = xT + (size_t)(B + b) * HW * C;

    __shared__ ull pool[6144];          // 49152 B: 4 x (A 4K + B 8K); red overlays
    char* poolc = (char*)pool;

    int tid = threadIdx.x;
    int w = tid >> 6, l = tid & 63;
    int quad = l >> 4, col = l & 15;
    int lrow = l >> 2, pos = l & 3;

    // staging source addresses (per-lane)
    int smA = w * 16 + lrow;                    // A rows 0..63
    int cdatA = pos ^ ((smA >> 1) & 3);
    const ushort* gA = X1 + (size_t)(pt * 64 + smA) * C + cdatA * 8;
    int smB0 = w * 16 + lrow;                   // B rows 0..63
    int cdatB0 = pos ^ ((smB0 >> 1) & 3);
    int q0 = qt * 128 + smB0; if (q0 >= HW) q0 = HW - 1;
    const ushort* gB0 = X2 + (size_t)q0 * C + cdatB0 * 8;
    int smB1 = 64 + w * 16 + lrow;              // B rows 64..127
    int cdatB1 = pos ^ ((smB1 >> 1) & 3);
    int q1 = qt * 128 + smB1; if (q1 >= HW) q1 = HW - 1;
    const ushort* gB1 = X2 + (size_t)q1 * C + cdatB1 * 8;

    int offA[4], offB[2];
#pragma unroll
    for (int i = 0; i < 4; ++i) {
        int p_loc = i * 16 + col;
        offA[i] = p_loc * 64 + ((quad ^ ((p_loc >> 1) & 3)) * 16);
    }
#pragma unroll
    for (int j = 0; j < 2; ++j) {
        int q_loc = w * 32 + j * 16 + col;
        offB[j] = 4096 + q_loc * 64 + ((quad ^ ((q_loc >> 1) & 3)) * 16);
    }

    floatx4 zero = {0.f, 0.f, 0.f, 0.f};
    floatx4 acc[4][2];
#pragma unroll
    for (int i = 0; i < 4; ++i)
#pragma unroll
        for (int j = 0; j < 2; ++j) acc[i][j] = zero;

    gemm_pp64<24>(gA, gB0, gB1, poolc, w, offA, offB, acc);

    // norms: sum of the two c-half partials
    const float* n1a = normp + (size_t)b * HW;
    const float* n1b = normp + (size_t)(128 + b) * HW;
    const float* n2a = normp + (size_t)(64 + b) * HW;
    const float* n2b = normp + (size_t)(192 + b) * HW;
    float n1v[4][4];
    float n2v[2]; bool vq[2]; int qg[2];
#pragma unroll
    for (int i = 0; i < 4; ++i)
#pragma unroll
        for (int r = 0; r < 4; ++r) {
            int p = pt * 64 + i * 16 + quad * 4 + r;   // always < 576
            n1v[i][r] = n1a[p] + n1b[p];
        }
#pragma unroll
    for (int j = 0; j < 2; ++j) {
        int q = qt * 128 + w * 32 + j * 16 + col;
        qg[j] = q;
        vq[j] = (q < HW);
        int qc = q < HW ? q : (HW - 1);
        n2v[j] = n2a[qc] + n2b[qc];
    }

    __syncthreads();
    typedef ull row65[65];
    row65* red = (row65*)pool;

    // pass 1: per-p min over this block's 128 q (64 writers per p)
#pragma unroll
    for (int i = 0; i < 4; ++i)
#pragma unroll
        for (int r = 0; r < 4; ++r) {
            int p_loc = i * 16 + quad * 4 + r;
            ull best = ~0ull;
#pragma unroll
            for (int j = 0; j < 2; ++j) {
                if (!vq[j]) continue;
                float d2 = fmaxf(n1v[i][r] + n2v[j] - 2.0f * acc[i][j][r], 0.0f);
                best = umin64(best, ((ull)__float_as_uint(d2) << 32) | (unsigned)qg[j]);
            }
            red[p_loc][w * 16 + col] = best;
        }
    __syncthreads();
    if (tid < 64) {
        ull m = ~0ull;
#pragma unroll
        for (int x = 0; x < 64; ++x) m = umin64(m, red[tid][x]);
        atomicMin(&nn1[(size_t)b * HW + pt * 64 + tid], m);
    }
    // pass 2: per-q min over this block's 64 p (pure shfl over quads, direct atomics)
#pragma unroll
    for (int j = 0; j < 2; ++j) {
        ull best = ~0ull;
#pragma unroll
        for (int i = 0; i < 4; ++i)
#pragma unroll
            for (int r = 0; r < 4; ++r) {
                float d2 = fmaxf(n1v[i][r] + n2v[j] - 2.0f * acc[i][j][r], 0.0f);
                unsigned p_glob = pt * 64 + i * 16 + quad * 4 + r;
                best = umin64(best, ((ull)__float_as_uint(d2) << 32) | p_glob);
            }
        best = umin64(best, __shfl_xor(best, 16, 64));
        best = umin64(best, __shfl_xor(best, 32, 64));
        if (quad == 0 && vq[j])
            atomicMin(&nn2[(size_t)b * HW + qg[j]], best);
    }
}

// ---------- top-k: one wave per (b,dir), keys in registers ----------
__global__ __launch_bounds__(64) void select_topk_wave(const ull* __restrict__ nn1,
                                                       const ull* __restrict__ nn2,
                                                       int* __restrict__ sel_p,
                                                       int* __restrict__ sel_q) {
    int b = blockIdx.x, dir = blockIdx.y;
    const ull* nn = dir ? nn2 : nn1;
    int lane = threadIdx.x;
    ull key[9]; uint qv[9];
#pragma unroll
    for (int r = 0; r < 9; ++r) {
        int p = r * 64 + lane;
        ull e = nn[(size_t)b * HW + p];
        key[r] = (e & 0xFFFFFFFF00000000ull) | (unsigned)p;
        qv[r] = (uint)(e & 0xFFFFFFFFu);
    }
    int* sp = sel_p + (dir * B + b) * K;
    int* sq = sel_q + (dir * B + b) * K;
    for (int it = 0; it < K; ++it) {
        ull m = key[0];
#pragma unroll
        for (int r = 1; r < 9; ++r) m = umin64(m, key[r]);
#pragma unroll
        for (int off = 32; off > 0; off >>= 1) m = umin64(m, __shfl_xor(m, off, 64));
#pragma unroll
        for (int r = 0; r < 9; ++r) {
            if (key[r] == m) {
                sp[it] = (int)(uint)(m & 0xFFFFFFFFu);
                sq[it] = (int)qv[r];
                key[r] = ~0ull;
            }
        }
    }
}

// ---------- gather into XgT[s][c][i], i = j*64 + b (coalesced writes) ----------
__global__ __launch_bounds__(256) void gather_jmajor(const ushort* __restrict__ xT,
                                                     const int* __restrict__ sel_p,
                                                     const int* __restrict__ sel_q,
                                                     ushort* __restrict__ XgT) {
    int j = blockIdx.x, s = blockIdx.y;
    int dir = s >> 1;
    int whichsrc = (s == 1 || s == 2) ? 1 : 0;
    const int* sel = (s & 1) ? sel_q : sel_p;
    __shared__ int sidx[64];
    __shared__ uint buf[64][33];
    int tid = threadIdx.x;
    if (tid < 64) sidx[tid] = sel[(dir * B + tid) * K + j];
    __syncthreads();
    int rb = tid >> 2, u = tid & 3;
    const ushort* srow = xT + (((size_t)whichsrc * B + rb) * HW + sidx[rb]) * C;
    int wv = tid >> 6, lb = tid & 63;
    ushort* obase = XgT + (size_t)s * C * NLOC + (size_t)j * 64 + lb;
    for (int ch = 0; ch < 12; ++ch) {
        __syncthreads();
        uint4 v0 = *(const uint4*)(srow + ch * 64 + u * 8);
        uint4 v1 = *(const uint4*)(srow + ch * 64 + (u + 4) * 8);
        buf[rb][u * 4 + 0] = v0.x; buf[rb][u * 4 + 1] = v0.y;
        buf[rb][u * 4 + 2] = v0.z; buf[rb][u * 4 + 3] = v0.w;
        buf[rb][(u + 4) * 4 + 0] = v1.x; buf[rb][(u + 4) * 4 + 1] = v1.y;
        buf[rb][(u + 4) * 4 + 2] = v1.z; buf[rb][(u + 4) * 4 + 3] = v1.w;
        __syncthreads();
#pragma unroll
        for (int st = 0; st < 16; ++st) {
            int cl = wv + st * 4;
            uint uv = buf[lb][cl >> 1];
            ushort val = (cl & 1) ? (ushort)(uv >> 16) : (ushort)(uv & 0xffffu);
            obase[(size_t)(ch * 64 + cl) * NLOC] = val;
        }
    }
}

// ---------- Mp[mat][split] = partial X^T X via MFMA, 64x128 tile, split-K=5 ----------
__global__ __launch_bounds__(256, 3) void ata_mfma(const ushort* __restrict__ XgT,
                                                   float* __restrict__ Mp) {
    int bx = blockIdx.x;                 // 0..71
    int mat = blockIdx.y, split = blockIdx.z;
    int rt = bx / 6, ct = bx % 6;        // rt 0..11 (64-row), ct 0..5 (128-col)
    const ushort* X = XgT + (size_t)mat * C * NLOC;

    __shared__ ull pool[6144];           // 49152 B
    char* poolc = (char*)pool;

    int tid = threadIdx.x;
    int w = tid >> 6, l = tid & 63;
    int quad = l >> 4, col = l & 15;
    int lrow = l >> 2, pos = l & 3;

    int smA = w * 16 + lrow;
    int cdatA = pos ^ ((smA >> 1) & 3);
    const ushort* gA = X + (size_t)(rt * 64 + smA) * NLOC + split * 640 + cdatA * 8;
    int smB0 = w * 16 + lrow;
    int cdatB0 = pos ^ ((smB0 >> 1) & 3);
    const ushort* gB0 = X + (size_t)(ct * 128 + smB0) * NLOC + split * 640 + cdatB0 * 8;
    int smB1 = 64 + w * 16 + lrow;
    int cdatB1 = pos ^ ((smB1 >> 1) & 3);
    const ushort* gB1 = X + (size_t)(ct * 128 + smB1) * NLOC + split * 640 + cdatB1 * 8;

    int offA[4], offB[2];
#pragma unroll
    for (int i = 0; i < 4; ++i) {
        int p_loc = i * 16 + col;
        offA[i] = p_loc * 64 + ((quad ^ ((p_loc >> 1) & 3)) * 16);
    }
#pragma unroll
    for (int j = 0; j < 2; ++j) {
        int q_loc = w * 32 + j * 16 + col;
        offB[j] = 4096 + q_loc * 64 + ((quad ^ ((q_loc >> 1) & 3)) * 16);
    }

    floatx4 zero = {0.f, 0.f, 0.f, 0.f};
    floatx4 acc[4][2];
#pragma unroll
    for (int i = 0; i < 4; ++i)
#pragma unroll
        for (int j = 0; j < 2; ++j) acc[i][j] = zero;

    gemm_pp64<20>(gA, gB0, gB1, poolc, w, offA, offB, acc);

    float* Mo = Mp + (size_t)(mat * 5 + split) * C * C;
#pragma unroll
    for (int i = 0; i < 4; ++i)
#pragma unroll
        for (int j = 0; j < 2; ++j)
#pragma unroll
            for (int r = 0; r < 4; ++r) {
                int row = rt * 64 + i * 16 + quad * 4 + r;
                int cc  = ct * 128 + w * 32 + j * 16 + col;
                Mo[(size_t)row * C + cc] = acc[i][j][r];
            }
}

// ---------- fp32 X^T X for pooled mats (4,5), n=64; colsum_pooled fused (rt==0) ----------
__global__ __launch_bounds__(256) void ata_pooled(const float* __restrict__ p1,
                                                  const float* __restrict__ p2,
                                                  float* __restrict__ M,
                                                  float* __restrict__ colsum) {
    int mat = 4 + blockIdx.z;
    const float* X = (mat == 4) ? p1 : p2;
    int n = B;
    float* Mo = M + (size_t)mat * C * C;
    int ct = blockIdx.x, rt = blockIdx.y;

    __shared__ float As[16][64];
    __shared__ float Bs[16][64];
    int tid = threadIdx.x;
    int tx = tid & 15, ty = tid >> 4;
    int lr = tid >> 4, lc = (tid & 15) * 4;

    float acc[4][4] = {};
    for (int k0 = 0; k0 < n; k0 += 16) {
        float4 av = *(const float4*)&X[(size_t)(k0 + lr) * C + rt * 64 + lc];
        float4 bv = *(const float4*)&X[(size_t)(k0 + lr) * C + ct * 64 + lc];
        __syncthreads();
        *(float4*)&As[lr][lc] = av;
        *(float4*)&Bs[lr][lc] = bv;
        __syncthreads();
#pragma unroll
        for (int kk = 0; kk < 16; ++kk) {
            float4 af = *(const float4*)&As[kk][ty * 4];
            float4 bf = *(const float4*)&Bs[kk][tx * 4];
            float a[4] = {af.x, af.y, af.z, af.w};
            float bb[4] = {bf.x, bf.y, bf.z, bf.w};
#pragma unroll
            for (int i = 0; i < 4; ++i)
#pragma unroll
                for (int j = 0; j < 4; ++j)
                    acc[i][j] = fmaf(a[i], bb[j], acc[i][j]);
        }
    }
#pragma unroll
    for (int i = 0; i < 4; ++i) {
        float4 o = {acc[i][0], acc[i][1], acc[i][2], acc[i][3]};
        *(float4*)&Mo[(size_t)(rt * 64 + ty * 4 + i) * C + ct * 64 + tx * 4] = o;
    }
    // fused colsum_pooled: rt==0 blocks cover their 64-col strip (same order as before)
    if (rt == 0 && tid < 64) {
        int c = ct * 64 + tid;
        float s = 0.f;
        for (int r = 0; r < B; ++r) s += X[(size_t)r * C + c];
        colsum[(size_t)mat * C + c] = s;
    }
}

// ---------- fused XgT scan: colsum (mats 0-3, order-preserving) + inv_local ----------
__global__ __launch_bounds__(256) void xgt_scan(const ushort* __restrict__ XgT,
                                                float* __restrict__ colsum,
                                                float* __restrict__ slots) {
    int pair = blockIdx.y;               // 0: mats(0,1)->INV1, 1: mats(2,3)->INV2
    int cb = blockIdx.x * 4;             // 4 c-rows per block
    int r = threadIdx.x >> 6, lane = threadIdx.x & 63;
    int c = cb + r;
    const ushort* rowA = XgT + ((size_t)(2 * pair) * C + c) * NLOC;
    const ushort* rowB = XgT + ((size_t)(2 * pair + 1) * C + c) * NLOC;
    float sa = 0.f, sb = 0.f, sinv = 0.f;
    for (int k = 0; k < K; ++k) {        // element order per lane identical to old colsum4
        int i = lane + 64 * k;
        float a = bf2f(rowA[i]);
        float b = bf2f(rowB[i]);
        sa += a;
        sb += b;
        float d = a - b;
        sinv = fmaf(d, d, sinv);
    }
    float ra = sa, rb = sb;
    for (int off = 32; off > 0; off >>= 1) {
        ra += __shfl_down(ra, off, 64);
        rb += __shfl_down(rb, off, 64);
    }
    if (lane == 0) {
        colsum[(2 * pair) * C + c] = ra;
        colsum[(2 * pair + 1) * C + c] = rb;
    }
    __shared__ float s4[4];
    float t = blk_reduce_sum(sinv, s4);
    if (threadIdx.x == 0) atomicAdd(&slots[(pair == 0) ? SLOT_INV1 : SLOT_INV2], t);
}

// ---------- cov term + fused std term (diag c==row handled in-loop) ----------
__global__ __launch_bounds__(256) void cov_kernel(const float* __restrict__ Mp,
                                                  const float* __restrict__ M,
                                                  const float* __restrict__ colsum,
                                                  float* __restrict__ slots) {
    int mat = blockIdx.y;
    float n = (mat < 4) ? (float)NLOC : (float)B;
    float invn1 = 1.0f / (n - 1.0f);
    __shared__ float cs_s[C];
    for (int c = threadIdx.x; c < C; c += 256) cs_s[c] = colsum[mat * C + c];
    __syncthreads();
    float s = 0.f, s_std = 0.f;
    int r0 = blockIdx.x * 16;
    for (int r = 0; r < 16; ++r) {
        int row = r0 + r;
        float csr = cs_s[row] / n;
        if (mat < 4) {
            const float* Mr0 = Mp + (size_t)(mat * 5 + 0) * C * C + (size_t)row * C;
            const float* Mr1 = Mp + (size_t)(mat * 5 + 1) * C * C + (size_t)row * C;
            const float* Mr2 = Mp + (size_t)(mat * 5 + 2) * C * C + (size_t)row * C;
            const float* Mr3 = Mp + (size_t)(mat * 5 + 3) * C * C + (size_t)row * C;
            const float* Mr4 = Mp + (size_t)(mat * 5 + 4) * C * C + (size_t)row * C;
            for (int c = threadIdx.x; c < C; c += 256) {
                float v = Mr0[c];
                v += Mr1[c]; v += Mr2[c]; v += Mr3[c]; v += Mr4[c];
                if (c != row) {
                    float cv = (v - csr * cs_s[c]) * invn1;
                    s = fmaf(cv, cv, s);
                } else {
                    float cs = cs_s[row];
                    float var = (v - cs * cs / n) / (n - 1.0f);
                    float sd = sqrtf(var + 1e-5f);
                    float g = 1.0f - sd;
                    s_std += (g > 0.f) ? g : 0.f;
                }
            }
        } else {
            const float* Mr = M + (size_t)mat * C * C + (size_t)row * C;
            for (int c = threadIdx.x; c < C; c += 256) {
                float v = Mr[c];
                if (c != row) {
                    float cv = (v - csr * cs_s[c]) * invn1;
                    s = fmaf(cv, cv, s);
                } else {
                    float cs = cs_s[row];
                    float var = (v - cs * cs / n) / (n - 1.0f);
                    float sd = sqrtf(var + 1e-5f);
                    float g = 1.0f - sd;
                    s_std += (g > 0.f) ? g : 0.f;
                }
            }
        }
    }
    __shared__ float s4[4];
    float t = blk_reduce_sum(s, s4);
    if (threadIdx.x == 0) atomicAdd(&slots[SLOT_COV + mat], t);
    __syncthreads();
    float t2 = blk_reduce_sum(s_std, s4);
    if (threadIdx.x == 0) atomicAdd(&slots[SLOT_STD + mat], t2);
}

// ---------- invariance (global) ----------
__global__ __launch_bounds__(256) void inv_global_kernel(const float* __restrict__ p1,
                                                         const float* __restrict__ p2,
                                                         float* __restrict__ slots) {
    int idx = blockIdx.x * 256 + threadIdx.x;
    int stride = gridDim.x * 256;
    float s = 0.f;
    for (int i = idx; i < B * C; i += stride) {
        float d = p1[i] - p2[i];
        s = fmaf(d, d, s);
    }
    __shared__ float s4[4];
    float t = blk_reduce_sum(s, s4);
    if (threadIdx.x == 0) atomicAdd(&slots[SLOT_INVG], t);
}

// ---------- final combine ----------
__global__ void final_kernel(const float* __restrict__ slots, float* __restrict__ out) {
    float std_t[6], cov_t[6];
    for (int m = 0; m < 6; ++m) {
        std_t[m] = slots[SLOT_STD + m] / (float)C * 0.5f;
        cov_t[m] = slots[SLOT_COV + m] / (float)C;
    }
    float inv_g = slots[SLOT_INVG] / (float)(B * C);
    float global_loss = 25.0f * inv_g + 25.0f * (std_t[4] + std_t[5]) + (cov_t[4] + cov_t[5]);
    float inv1 = 25.0f * slots[SLOT_INV1] / (float)(NLOC * C);
    float inv2 = 25.0f * slots[SLOT_INV2] / (float)(NLOC * C);
    float var1 = 25.0f * (std_t[0] + std_t[1]);
    float var2 = 25.0f * (std_t[2] + std_t[3]);
    float cov1 = cov_t[0] + cov_t[1];
    float cov2 = cov_t[2] + cov_t[3];
    float local_loss = (inv1 + inv2) * 0.5f + (var1 + var2) * 0.5f + (cov1 + cov2) * 0.5f;
    out[0] = 0.5f * global_loss + 0.5f * local_loss;
}

extern "C" void kernel_launch(void* const* d_in, const int* in_sizes, int n_in,
                              void* d_out, int out_size, void* d_ws, size_t ws_size,
                              hipStream_t stream) {
    const float* spatial_1 = (const float*)d_in[0];
    const float* pooled_1  = (const float*)d_in[1];
    const float* spatial_2 = (const float*)d_in[2];
    const float* pooled_2  = (const float*)d_in[3];
    float* out = (float*)d_out;

    char* ws = (char*)d_ws;
    float*  slots  = (float*)(ws + OFF_SLOTS);
    float*  colsum = (float*)(ws + OFF_COLSUM);
    ull*    nn1    = (ull*)(ws + OFF_NN1);
    ull*    nn2    = (ull*)(ws + OFF_NN2);
    int*    sel_p  = (int*)(ws + OFF_SELP);
    int*    sel_q  = (int*)(ws + OFF_SELQ);
    ushort* xT     = (ushort*)(ws + OFF_XT);
    float*  Mp     = (float*)(ws + OFF_MP);   // overlays xT (dead after gather)
    ushort* XgT    = (ushort*)(ws + OFF_XGT);
    float*  M      = (float*)(ws + OFF_M);
    float*  normp  = (float*)(ws + OFF_M);    // [2 halves][2*64][576] overlay in mats 0-3 region

    hipMemsetAsync(ws, 0, OFF_NN1, stream);                          // slots + colsum
    hipMemsetAsync(ws + OFF_NN1, 0xFF, OFF_SELP - OFF_NN1, stream);  // nn keys

    convert_kernel<<<dim3(18, 128), 256, 0, stream>>>(spatial_1, spatial_2, xT, normp);
    cdist_mfma<<<2880, 256, 0, stream>>>(xT, normp, nn1, nn2);
    select_topk_wave<<<dim3(B, 2), 64, 0, stream>>>(nn1, nn2, sel_p, sel_q);
    gather_jmajor<<<dim3(K, 4), 256, 0, stream>>>(xT, sel_p, sel_q, XgT);
    ata_mfma<<<dim3(72, 4, 5), 256, 0, stream>>>(XgT, Mp);
    ata_pooled<<<dim3(12, 12, 2), 256, 0, stream>>>(pooled_1, pooled_2, M, colsum);
    xgt_scan<<<dim3(192, 2), 256, 0, stream>>>(XgT, colsum, slots);
    cov_kernel<<<dim3(48, 6), 256, 0, stream>>>(Mp, M, colsum, slots);
    inv_global_kernel<<<dim3(96), 256, 0, stream>>>(pooled_1, pooled_2, slots);
    final_kernel<<<1, 1, 0, stream>>>(slots, out);
}

// Round 6
// 436.840 us; speedup vs baseline: 1.1062x; 1.0259x over previous
//
#include <hip/hip_runtime.h>
#include <stdint.h>

typedef unsigned long long ull;
typedef unsigned int uint;
typedef unsigned short ushort;

typedef __attribute__((ext_vector_type(8))) short short8;
typedef __attribute__((ext_vector_type(4))) float floatx4;

#define B   64
#define C   768
#define HW  576
#define K   50
#define NLOC (B*K)          // 3200

// ---- workspace layout (bytes) ----
#define OFF_SLOTS   0            // 64 floats
#define OFF_COLSUM  256          // 6*768*4 = 18432
#define OFF_NN1     18688        // 64*576*8 = 294912
#define OFF_NN2     313600       // 294912
#define OFF_SELP    608512       // 2*64*50*4 = 25600
#define OFF_SELQ    634112       // 25600
#define OFF_XT      954624       // 2*64*576*768*2 = 113246208  (dead after gather -> reused as Mp)
#define OFF_MP      OFF_XT       // 4 mats * 4 splits * 768*768*4 = 37748736 (fits in XT region)
#define OFF_XGT     114200832    // 4*768*3200*2 = 19660800
#define OFF_M       133861632    // 6*768*768*4 (mats 4,5 used; mats 0-3 region = normp overlay)
// total 148017408

#define SLOT_INVG 0
#define SLOT_STD  1   // +mat (0..5)
#define SLOT_COV  7   // +mat (0..5)
#define SLOT_INV1 13
#define SLOT_INV2 14

__device__ __forceinline__ ull umin64(ull a, ull b) { return a < b ? a : b; }

__device__ __forceinline__ float bf2f_lo(uint u) { return __uint_as_float(u << 16); }
__device__ __forceinline__ float bf2f_hi(uint u) { return __uint_as_float(u & 0xffff0000u); }
__device__ __forceinline__ float bf2f(ushort u) { return __uint_as_float(((uint)u) << 16); }

__device__ __forceinline__ ushort f2bf(float f) {
    uint u = __float_as_uint(f);
    uint r = (u + 0x7fffu + ((u >> 16) & 1u)) >> 16;   // RNE
    return (ushort)r;
}

__device__ __forceinline__ float blk_reduce_sum(float v, float* s4) {
    for (int off = 32; off > 0; off >>= 1) v += __shfl_down(v, off, 64);
    int lane = threadIdx.x & 63, w = threadIdx.x >> 6;
    if (lane == 0) s4[w] = v;
    __syncthreads();
    float r = 0.f;
    if (threadIdx.x == 0) r = s4[0] + s4[1] + s4[2] + s4[3];
    return r;
}

// ---------- convert fp32 [b][c][p] -> bf16 xT[which][b][p][c] + fused norm partials ----------
// (kept: measured pattern-level wall ~2.25 TB/s across 4 structural variants)
__global__ __launch_bounds__(256) void convert_kernel(const float* __restrict__ x1,
                                                      const float* __restrict__ x2,
                                                      ushort* __restrict__ xT,
                                                      float* __restrict__ normp) {
    int z = blockIdx.y;
    int which = z >> 6, b = z & 63;
    int half = blockIdx.x & 1;
    int pt = blockIdx.x >> 1;          // 0..8
    int p0 = pt * 64, c0 = half * 384;
    const float* X = (which ? x2 : x1) + ((size_t)b * C + c0) * HW + p0;

    __shared__ ushort tile[64][392];   // [p][c], 784B row stride
    __shared__ float nlds[64][4];

    int t = threadIdx.x;
    int pq = t & 15, cq = t >> 4;      // p-quad (16), c-quad (16)
    int w = t >> 6;

    float ss[4] = {0.f, 0.f, 0.f, 0.f};

#pragma unroll
    for (int pass = 0; pass < 6; ++pass) {
        floatx4 v[4];
#pragma unroll
        for (int i = 0; i < 4; ++i)
            v[i] = *(const floatx4*)(X + (size_t)(pass * 64 + 4 * cq + i) * HW + 4 * pq);
#pragma unroll
        for (int j = 0; j < 4; ++j) {
            ushort u0 = f2bf(v[0][j]), u1 = f2bf(v[1][j]);
            ushort u2 = f2bf(v[2][j]), u3 = f2bf(v[3][j]);
            ushort4 uu; uu.x = u0; uu.y = u1; uu.z = u2; uu.w = u3;
            *(ushort4*)&tile[4 * pq + j][pass * 64 + 4 * cq] = uu;
            float r0 = bf2f(u0), r1 = bf2f(u1), r2 = bf2f(u2), r3 = bf2f(u3);
            ss[j] = fmaf(r0, r0, ss[j]); ss[j] = fmaf(r1, r1, ss[j]);
            ss[j] = fmaf(r2, r2, ss[j]); ss[j] = fmaf(r3, r3, ss[j]);
        }
    }
#pragma unroll
    for (int j = 0; j < 4; ++j) {
        ss[j] += __shfl_xor(ss[j], 16, 64);
        ss[j] += __shfl_xor(ss[j], 32, 64);
    }
    if ((t & 63) < 16) {
#pragma unroll
        for (int j = 0; j < 4; ++j) nlds[4 * pq + j][w] = ss[j];
    }
    __syncthreads();

    ushort* dst = xT + (((size_t)which * B + b) * HW + p0) * C + c0;
    const char* tb = (const char*)tile;
#pragma unroll
    for (int step = 0; step < 12; ++step) {
        int ib = (step * 256 + t) * 16;
        int p = ib / 768, cb = ib % 768;
        short8 vv = *(const short8*)(tb + (size_t)p * 784 + cb);
        *(short8*)(dst + (size_t)p * C + (cb >> 1)) = vv;
    }
    if (t < 64) {
        float nv = nlds[t][0] + nlds[t][1] + nlds[t][2] + nlds[t][3];
        normp[((size_t)half * 128 + which * 64 + b) * HW + p0 + t] = nv;
    }
}

// ---------- 64x128-tile, 4-wave, 4-deep pipelined MFMA K-loop ----------
template<int NG>
__device__ __forceinline__ void gemm_pp64(const ushort* gA, const ushort* gB0, const ushort* gB1,
                                          char* pool, int w,
                                          const int (&offA)[4], const int (&offB)[2],
                                          floatx4 (&acc)[4][2]) {
    auto issue = [&](int h) {
        char* buf = pool + (h & 3) * 12288;
        __builtin_amdgcn_global_load_lds(
            (const __attribute__((address_space(1))) void*)(gA + h * 32),
            (__attribute__((address_space(3))) void*)(buf + w * 1024), 16, 0, 0);
        __builtin_amdgcn_global_load_lds(
            (const __attribute__((address_space(1))) void*)(gB0 + h * 32),
            (__attribute__((address_space(3))) void*)(buf + 4096 + w * 1024), 16, 0, 0);
        __builtin_amdgcn_global_load_lds(
            (const __attribute__((address_space(1))) void*)(gB1 + h * 32),
            (__attribute__((address_space(3))) void*)(buf + 4096 + (4 + w) * 1024), 16, 0, 0);
    };
    issue(0); issue(1); issue(2);
    for (int h = 0; h < NG; ++h) {
        if (h < NG - 2)       asm volatile("s_waitcnt vmcnt(6)" ::: "memory");
        else if (h == NG - 2) asm volatile("s_waitcnt vmcnt(3)" ::: "memory");
        else                  asm volatile("s_waitcnt vmcnt(0)" ::: "memory");
        __builtin_amdgcn_s_barrier();
        if (h + 3 < NG) issue(h + 3);
        __builtin_amdgcn_sched_barrier(0);
        const char* buf = pool + (h & 3) * 12288;
        short8 a[4], bb[2];
#pragma unroll
        for (int i = 0; i < 4; ++i) a[i] = *(const short8*)(buf + offA[i]);
#pragma unroll
        for (int j = 0; j < 2; ++j) bb[j] = *(const short8*)(buf + offB[j]);
#pragma unroll
        for (int i = 0; i < 4; ++i)
#pragma unroll
            for (int j = 0; j < 2; ++j)
                acc[i][j] = __builtin_amdgcn_mfma_f32_16x16x32_bf16(a[i], bb[j], acc[i][j], 0, 0, 0);
    }
}

// ---------- cdist Gram via MFMA, 64x128 tile, XCD-swizzled 1-D grid ----------
__global__ __launch_bounds__(256, 3) void cdist_mfma(const ushort* __restrict__ xT,
                                                     const float* __restrict__ normp,
                                                     ull* __restrict__ nn1,
                                                     ull* __restrict__ nn2) {
    int id = blockIdx.x;
    int xcd = id & 7, slot = id >> 3;
    int b = xcd + 8 * (slot / 45);      // all 45 tiles of a batch share one XCD slot
    int t = slot % 45;
    int qt = t % 5, pt = t / 5;         // pt 0..8 (exact 9x64=576), qt 0..4

    const ushort* X1 = xT + (size_t)b * HW * C;
    const ushort* X2 = xT + (size_t)(B + b) * HW * C;

    __shared__ ull pool[6144];          // 49152 B: 4 x (A 4K + B 8K); red overlays
    char* poolc = (char*)pool;

    int tid = threadIdx.x;
    int w = tid >> 6, l = tid & 63;
    int quad = l >> 4, col = l & 15;
    int lrow = l >> 2, pos = l & 3;

    int smA = w * 16 + lrow;                    // A rows 0..63
    int cdatA = pos ^ ((smA >> 1) & 3);
    const ushort* gA = X1 + (size_t)(pt * 64 + smA) * C + cdatA * 8;
    int smB0 = w * 16 + lrow;                   // B rows 0..63
    int cdatB0 = pos ^ ((smB0 >> 1) & 3);
    int q0 = qt * 128 + smB0; if (q0 >= HW) q0 = HW - 1;
    const ushort* gB0 = X2 + (size_t)q0 * C + cdatB0 * 8;
    int smB1 = 64 + w * 16 + lrow;              // B rows 64..127
    int cdatB1 = pos ^ ((smB1 >> 1) & 3);
    int q1 = qt * 128 + smB1; if (q1 >= HW) q1 = HW - 1;
    const ushort* gB1 = X2 + (size_t)q1 * C + cdatB1 * 8;

    int offA[4], offB[2];
#pragma unroll
    for (int i = 0; i < 4; ++i) {
        int p_loc = i * 16 + col;
        offA[i] = p_loc * 64 + ((quad ^ ((p_loc >> 1) & 3)) * 16);
    }
#pragma unroll
    for (int j = 0; j < 2; ++j) {
        int q_loc = w * 32 + j * 16 + col;
        offB[j] = 4096 + q_loc * 64 + ((quad ^ ((q_loc >> 1) & 3)) * 16);
    }

    floatx4 zero = {0.f, 0.f, 0.f, 0.f};
    floatx4 acc[4][2];
#pragma unroll
    for (int i = 0; i < 4; ++i)
#pragma unroll
        for (int j = 0; j < 2; ++j) acc[i][j] = zero;

    gemm_pp64<24>(gA, gB0, gB1, poolc, w, offA, offB, acc);

    const float* n1a = normp + (size_t)b * HW;
    const float* n1b = normp + (size_t)(128 + b) * HW;
    const float* n2a = normp + (size_t)(64 + b) * HW;
    const float* n2b = normp + (size_t)(192 + b) * HW;
    float n1v[4][4];
    float n2v[2]; bool vq[2]; int qg[2];
#pragma unroll
    for (int i = 0; i < 4; ++i)
#pragma unroll
        for (int r = 0; r < 4; ++r) {
            int p = pt * 64 + i * 16 + quad * 4 + r;   // always < 576
            n1v[i][r] = n1a[p] + n1b[p];
        }
#pragma unroll
    for (int j = 0; j < 2; ++j) {
        int q = qt * 128 + w * 32 + j * 16 + col;
        qg[j] = q;
        vq[j] = (q < HW);
        int qc = q < HW ? q : (HW - 1);
        n2v[j] = n2a[qc] + n2b[qc];
    }

    __syncthreads();
    typedef ull row65[65];
    row65* red = (row65*)pool;

    // pass 1: per-p min over this block's 128 q
#pragma unroll
    for (int i = 0; i < 4; ++i)
#pragma unroll
        for (int r = 0; r < 4; ++r) {
            int p_loc = i * 16 + quad * 4 + r;
            ull best = ~0ull;
#pragma unroll
            for (int j = 0; j < 2; ++j) {
                if (!vq[j]) continue;
                float d2 = fmaxf(n1v[i][r] + n2v[j] - 2.0f * acc[i][j][r], 0.0f);
                best = umin64(best, ((ull)__float_as_uint(d2) << 32) | (unsigned)qg[j]);
            }
            red[p_loc][w * 16 + col] = best;
        }
    __syncthreads();
    if (tid < 64) {
        ull m = ~0ull;
#pragma unroll
        for (int x = 0; x < 64; ++x) m = umin64(m, red[tid][x]);
        atomicMin(&nn1[(size_t)b * HW + pt * 64 + tid], m);
    }
    // pass 2: per-q min over this block's 64 p
#pragma unroll
    for (int j = 0; j < 2; ++j) {
        ull best = ~0ull;
#pragma unroll
        for (int i = 0; i < 4; ++i)
#pragma unroll
            for (int r = 0; r < 4; ++r) {
                float d2 = fmaxf(n1v[i][r] + n2v[j] - 2.0f * acc[i][j][r], 0.0f);
                unsigned p_glob = pt * 64 + i * 16 + quad * 4 + r;
                best = umin64(best, ((ull)__float_as_uint(d2) << 32) | p_glob);
            }
        best = umin64(best, __shfl_xor(best, 16, 64));
        best = umin64(best, __shfl_xor(best, 32, 64));
        if (quad == 0 && vq[j])
            atomicMin(&nn2[(size_t)b * HW + qg[j]], best);
    }
}

// ---------- top-k: one wave per (b,dir), keys in registers ----------
__global__ __launch_bounds__(64) void select_topk_wave(const ull* __restrict__ nn1,
                                                       const ull* __restrict__ nn2,
                                                       int* __restrict__ sel_p,
                                                       int* __restrict__ sel_q) {
    int b = blockIdx.x, dir = blockIdx.y;
    const ull* nn = dir ? nn2 : nn1;
    int lane = threadIdx.x;
    ull key[9]; uint qv[9];
#pragma unroll
    for (int r = 0; r < 9; ++r) {
        int p = r * 64 + lane;
        ull e = nn[(size_t)b * HW + p];
        key[r] = (e & 0xFFFFFFFF00000000ull) | (unsigned)p;
        qv[r] = (uint)(e & 0xFFFFFFFFu);
    }
    int* sp = sel_p + (dir * B + b) * K;
    int* sq = sel_q + (dir * B + b) * K;
    for (int it = 0; it < K; ++it) {
        ull m = key[0];
#pragma unroll
        for (int r = 1; r < 9; ++r) m = umin64(m, key[r]);
#pragma unroll
        for (int off = 32; off > 0; off >>= 1) m = umin64(m, __shfl_xor(m, off, 64));
#pragma unroll
        for (int r = 0; r < 9; ++r) {
            if (key[r] == m) {
                sp[it] = (int)(uint)(m & 0xFFFFFFFFu);
                sq[it] = (int)qv[r];
                key[r] = ~0ull;
            }
        }
    }
}

// ---------- gather into XgT[s][c][i], i = j*64 + b (uint-paired coalesced writes) ----------
__global__ __launch_bounds__(256) void gather_jmajor(const ushort* __restrict__ xT,
                                                     const int* __restrict__ sel_p,
                                                     const int* __restrict__ sel_q,
                                                     ushort* __restrict__ XgT) {
    int j = blockIdx.x, s = blockIdx.y;
    int dir = s >> 1;
    int whichsrc = (s == 1 || s == 2) ? 1 : 0;
    const int* sel = (s & 1) ? sel_q : sel_p;
    __shared__ int sidx[64];
    __shared__ uint buf[64][33];
    int tid = threadIdx.x;
    if (tid < 64) sidx[tid] = sel[(dir * B + tid) * K + j];
    __syncthreads();
    int rb = tid >> 2, u = tid & 3;
    const ushort* srow = xT + (((size_t)whichsrc * B + rb) * HW + sidx[rb]) * C;
    int wv = tid >> 6;
    int half32 = (tid >> 5) & 1;
    int lb2 = tid & 31;                 // b-pair index: lanes cover b = 2*lb2, 2*lb2+1
    ushort* obase0 = XgT + (size_t)s * C * NLOC + (size_t)j * 64;
    for (int ch = 0; ch < 12; ++ch) {
        __syncthreads();
        uint4 v0 = *(const uint4*)(srow + ch * 64 + u * 8);
        uint4 v1 = *(const uint4*)(srow + ch * 64 + (u + 4) * 8);
        buf[rb][u * 4 + 0] = v0.x; buf[rb][u * 4 + 1] = v0.y;
        buf[rb][u * 4 + 2] = v0.z; buf[rb][u * 4 + 3] = v0.w;
        buf[rb][(u + 4) * 4 + 0] = v1.x; buf[rb][(u + 4) * 4 + 1] = v1.y;
        buf[rb][(u + 4) * 4 + 2] = v1.z; buf[rb][(u + 4) * 4 + 3] = v1.w;
        __syncthreads();
#pragma unroll
        for (int st = 0; st < 8; ++st) {
            int cl = wv * 2 + half32 + st * 8;     // 0..63
            uint uv0 = buf[2 * lb2][cl >> 1];
            uint uv1 = buf[2 * lb2 + 1][cl >> 1];
            ushort a = (cl & 1) ? (ushort)(uv0 >> 16) : (ushort)(uv0 & 0xffffu);
            ushort b2 = (cl & 1) ? (ushort)(uv1 >> 16) : (ushort)(uv1 & 0xffffu);
            uint wr = (uint)a | ((uint)b2 << 16);
            *(uint*)(obase0 + (size_t)(ch * 64 + cl) * NLOC + 2 * lb2) = wr;
        }
    }
}

// ---------- Mp[mat][split] = partial X^T X via MFMA, upper-triangle 64x128 tiles, split-K=4 ----------
__global__ __launch_bounds__(256, 3) void ata_mfma(const ushort* __restrict__ XgT,
                                                   float* __restrict__ Mp) {
    int bx = blockIdx.x;                 // 0..46 (upper-triangle tile list)
    int mat = blockIdx.y, split = blockIdx.z;
    int ct, rt;
    if (bx < 3)       { ct = 0; rt = bx; }
    else if (bx < 8)  { ct = 1; rt = bx - 3; }
    else if (bx < 15) { ct = 2; rt = bx - 8; }
    else if (bx < 24) { ct = 3; rt = bx - 15; }
    else if (bx < 35) { ct = 4; rt = bx - 24; }
    else              { ct = 5; rt = bx - 35; }
    const ushort* X = XgT + (size_t)mat * C * NLOC;

    __shared__ ull pool[6144];           // 49152 B
    char* poolc = (char*)pool;

    int tid = threadIdx.x;
    int w = tid >> 6, l = tid & 63;
    int quad = l >> 4, col = l & 15;
    int lrow = l >> 2, pos = l & 3;

    int smA = w * 16 + lrow;
    int cdatA = pos ^ ((smA >> 1) & 3);
    const ushort* gA = X + (size_t)(rt * 64 + smA) * NLOC + split * 800 + cdatA * 8;
    int smB0 = w * 16 + lrow;
    int cdatB0 = pos ^ ((smB0 >> 1) & 3);
    const ushort* gB0 = X + (size_t)(ct * 128 + smB0) * NLOC + split * 800 + cdatB0 * 8;
    int smB1 = 64 + w * 16 + lrow;
    int cdatB1 = pos ^ ((smB1 >> 1) & 3);
    const ushort* gB1 = X + (size_t)(ct * 128 + smB1) * NLOC + split * 800 + cdatB1 * 8;

    int offA[4], offB[2];
#pragma unroll
    for (int i = 0; i < 4; ++i) {
        int p_loc = i * 16 + col;
        offA[i] = p_loc * 64 + ((quad ^ ((p_loc >> 1) & 3)) * 16);
    }
#pragma unroll
    for (int j = 0; j < 2; ++j) {
        int q_loc = w * 32 + j * 16 + col;
        offB[j] = 4096 + q_loc * 64 + ((quad ^ ((q_loc >> 1) & 3)) * 16);
    }

    floatx4 zero = {0.f, 0.f, 0.f, 0.f};
    floatx4 acc[4][2];
#pragma unroll
    for (int i = 0; i < 4; ++i)
#pragma unroll
        for (int j = 0; j < 2; ++j) acc[i][j] = zero;

    gemm_pp64<25>(gA, gB0, gB1, poolc, w, offA, offB, acc);

    float* Mo = Mp + (size_t)(mat * 4 + split) * C * C;
#pragma unroll
    for (int i = 0; i < 4; ++i)
#pragma unroll
        for (int j = 0; j < 2; ++j)
#pragma unroll
            for (int r = 0; r < 4; ++r) {
                int row = rt * 64 + i * 16 + quad * 4 + r;
                int cc  = ct * 128 + w * 32 + j * 16 + col;
                Mo[(size_t)row * C + cc] = acc[i][j][r];
            }
}

// ---------- fp32 X^T X for pooled mats (4,5); colsum (rt==0) + inv_global (z==0,rt==0) fused ----------
__global__ __launch_bounds__(256) void ata_pooled(const float* __restrict__ p1,
                                                  const float* __restrict__ p2,
                                                  float* __restrict__ M,
                                                  float* __restrict__ colsum,
                                                  float* __restrict__ slots) {
    int mat = 4 + blockIdx.z;
    const float* X = (mat == 4) ? p1 : p2;
    int n = B;
    float* Mo = M + (size_t)mat * C * C;
    int ct = blockIdx.x, rt = blockIdx.y;

    __shared__ float As[16][64];
    __shared__ float Bs[16][64];
    int tid = threadIdx.x;
    int tx = tid & 15, ty = tid >> 4;
    int lr = tid >> 4, lc = (tid & 15) * 4;

    float acc[4][4] = {};
    for (int k0 = 0; k0 < n; k0 += 16) {
        float4 av = *(const float4*)&X[(size_t)(k0 + lr) * C + rt * 64 + lc];
        float4 bv = *(const float4*)&X[(size_t)(k0 + lr) * C + ct * 64 + lc];
        __syncthreads();
        *(float4*)&As[lr][lc] = av;
        *(float4*)&Bs[lr][lc] = bv;
        __syncthreads();
#pragma unroll
        for (int kk = 0; kk < 16; ++kk) {
            float4 af = *(const float4*)&As[kk][ty * 4];
            float4 bf = *(const float4*)&Bs[kk][tx * 4];
            float a[4] = {af.x, af.y, af.z, af.w};
            float bb[4] = {bf.x, bf.y, bf.z, bf.w};
#pragma unroll
            for (int i = 0; i < 4; ++i)
#pragma unroll
                for (int j = 0; j < 4; ++j)
                    acc[i][j] = fmaf(a[i], bb[j], acc[i][j]);
        }
    }
#pragma unroll
    for (int i = 0; i < 4; ++i) {
        float4 o = {acc[i][0], acc[i][1], acc[i][2], acc[i][3]};
        *(float4*)&Mo[(size_t)(rt * 64 + ty * 4 + i) * C + ct * 64 + tx * 4] = o;
    }
    if (rt == 0 && tid < 64) {
        int c = ct * 64 + tid;
        float s = 0.f;
        for (int r = 0; r < B; ++r) s += X[(size_t)r * C + c];
        colsum[(size_t)mat * C + c] = s;
    }
    // fused inv_global: z==0, rt==0 blocks each cover a 64-col strip over all rows
    if (blockIdx.z == 0 && rt == 0) {
        int c = ct * 64 + (tid & 63);
        int r0_ = tid >> 6;
        float s = 0.f;
        for (int r = r0_; r < B; r += 4) {
            float d = p1[(size_t)r * C + c] - p2[(size_t)r * C + c];
            s = fmaf(d, d, s);
        }
        __shared__ float s4b[4];
        float t = blk_reduce_sum(s, s4b);
        if (tid == 0) atomicAdd(&slots[SLOT_INVG], t);
    }
}

// ---------- fused XgT scan: colsum (mats 0-3) + inv_local ----------
__global__ __launch_bounds__(256) void xgt_scan(const ushort* __restrict__ XgT,
                                                float* __restrict__ colsum,
                                                float* __restrict__ slots) {
    int pair = blockIdx.y;               // 0: mats(0,1)->INV1, 1: mats(2,3)->INV2
    int cb = blockIdx.x * 4;
    int r = threadIdx.x >> 6, lane = threadIdx.x & 63;
    int c = cb + r;
    const ushort* rowA = XgT + ((size_t)(2 * pair) * C + c) * NLOC;
    const ushort* rowB = XgT + ((size_t)(2 * pair + 1) * C + c) * NLOC;
    float sa = 0.f, sb = 0.f, sinv = 0.f;
    for (int k = 0; k < K; ++k) {
        int i = lane + 64 * k;
        float a = bf2f(rowA[i]);
        float b = bf2f(rowB[i]);
        sa += a;
        sb += b;
        float d = a - b;
        sinv = fmaf(d, d, sinv);
    }
    float ra = sa, rb = sb;
    for (int off = 32; off > 0; off >>= 1) {
        ra += __shfl_down(ra, off, 64);
        rb += __shfl_down(rb, off, 64);
    }
    if (lane == 0) {
        colsum[(2 * pair) * C + c] = ra;
        colsum[(2 * pair + 1) * C + c] = rb;
    }
    __shared__ float s4[4];
    float t = blk_reduce_sum(sinv, s4);
    if (threadIdx.x == 0) atomicAdd(&slots[(pair == 0) ? SLOT_INV1 : SLOT_INV2], t);
}

// ---------- cov (upper-only x2, mirrored row pairing) + fused std (diag) ----------
__global__ __launch_bounds__(256) void cov_kernel(const float* __restrict__ Mp,
                                                  const float* __restrict__ M,
                                                  const float* __restrict__ colsum,
                                                  float* __restrict__ slots) {
    int mat = blockIdx.y;
    float n = (mat < 4) ? (float)NLOC : (float)B;
    float invn1 = 1.0f / (n - 1.0f);
    __shared__ float cs_s[C];
    for (int c = threadIdx.x; c < C; c += 256) cs_s[c] = colsum[mat * C + c];
    __syncthreads();
    float s = 0.f, s_std = 0.f;
    int bx = blockIdx.x;                 // 0..47; rows [8bx,8bx+8) U [752-8bx+?, ...]
    for (int rr = 0; rr < 16; ++rr) {
        int row = (rr < 8) ? (8 * bx + rr) : (768 - 8 * bx - 16 + rr);
        float csr = cs_s[row] / n;
        if (mat < 4) {
            const float* Mr0 = Mp + (size_t)(mat * 4 + 0) * C * C + (size_t)row * C;
            const float* Mr1 = Mp + (size_t)(mat * 4 + 1) * C * C + (size_t)row * C;
            const float* Mr2 = Mp + (size_t)(mat * 4 + 2) * C * C + (size_t)row * C;
            const float* Mr3 = Mp + (size_t)(mat * 4 + 3) * C * C + (size_t)row * C;
            if (threadIdx.x == 0) {
                float v = Mr0[row];
                v += Mr1[row]; v += Mr2[row]; v += Mr3[row];
                float cs = cs_s[row];
                float var = (v - cs * cs / n) / (n - 1.0f);
                float g = 1.0f - sqrtf(var + 1e-5f);
                s_std += (g > 0.f) ? g : 0.f;
            }
            for (int c = row + 1 + threadIdx.x; c < C; c += 256) {
                float v = Mr0[c];
                v += Mr1[c]; v += Mr2[c]; v += Mr3[c];
                float cv = (v - csr * cs_s[c]) * invn1;
                s = fmaf(cv, cv, s);
            }
        } else {
            const float* Mr = M + (size_t)mat * C * C + (size_t)row * C;
            if (threadIdx.x == 0) {
                float v = Mr[row];
                float cs = cs_s[row];
                float var = (v - cs * cs / n) / (n - 1.0f);
                float g = 1.0f - sqrtf(var + 1e-5f);
                s_std += (g > 0.f) ? g : 0.f;
            }
            for (int c = row + 1 + threadIdx.x; c < C; c += 256) {
                float cv = (Mr[c] - csr * cs_s[c]) * invn1;
                s = fmaf(cv, cv, s);
            }
        }
    }
    s *= 2.0f;                            // off-diag sum = 2 x upper (bit-symmetric cv)
    __shared__ float s4[4];
    float t = blk_reduce_sum(s, s4);
    if (threadIdx.x == 0) atomicAdd(&slots[SLOT_COV + mat], t);
    __syncthreads();
    float t2 = blk_reduce_sum(s_std, s4);
    if (threadIdx.x == 0) atomicAdd(&slots[SLOT_STD + mat], t2);
}

// ---------- final combine ----------
__global__ void final_kernel(const float* __restrict__ slots, float* __restrict__ out) {
    float std_t[6], cov_t[6];
    for (int m = 0; m < 6; ++m) {
        std_t[m] = slots[SLOT_STD + m] / (float)C * 0.5f;
        cov_t[m] = slots[SLOT_COV + m] / (float)C;
    }
    float inv_g = slots[SLOT_INVG] / (float)(B * C);
    float global_loss = 25.0f * inv_g + 25.0f * (std_t[4] + std_t[5]) + (cov_t[4] + cov_t[5]);
    float inv1 = 25.0f * slots[SLOT_INV1] / (float)(NLOC * C);
    float inv2 = 25.0f * slots[SLOT_INV2] / (float)(NLOC * C);
    float var1 = 25.0f * (std_t[0] + std_t[1]);
    float var2 = 25.0f * (std_t[2] + std_t[3]);
    float cov1 = cov_t[0] + cov_t[1];
    float cov2 = cov_t[2] + cov_t[3];
    float local_loss = (inv1 + inv2) * 0.5f + (var1 + var2) * 0.5f + (cov1 + cov2) * 0.5f;
    out[0] = 0.5f * global_loss + 0.5f * local_loss;
}

extern "C" void kernel_launch(void* const* d_in, const int* in_sizes, int n_in,
                              void* d_out, int out_size, void* d_ws, size_t ws_size,
                              hipStream_t stream) {
    const float* spatial_1 = (const float*)d_in[0];
    const float* pooled_1  = (const float*)d_in[1];
    const float* spatial_2 = (const float*)d_in[2];
    const float* pooled_2  = (const float*)d_in[3];
    float* out = (float*)d_out;

    char* ws = (char*)d_ws;
    float*  slots  = (float*)(ws + OFF_SLOTS);
    float*  colsum = (float*)(ws + OFF_COLSUM);
    ull*    nn1    = (ull*)(ws + OFF_NN1);
    ull*    nn2    = (ull*)(ws + OFF_NN2);
    int*    sel_p  = (int*)(ws + OFF_SELP);
    int*    sel_q  = (int*)(ws + OFF_SELQ);
    ushort* xT     = (ushort*)(ws + OFF_XT);
    float*  Mp     = (float*)(ws + OFF_MP);   // overlays xT (dead after gather)
    ushort* XgT    = (ushort*)(ws + OFF_XGT);
    float*  M      = (float*)(ws + OFF_M);
    float*  normp  = (float*)(ws + OFF_M);    // [2 halves][2*64][576] overlay in mats 0-3 region

    hipMemsetAsync(ws, 0, OFF_NN1, stream);                          // slots + colsum
    hipMemsetAsync(ws + OFF_NN1, 0xFF, OFF_SELP - OFF_NN1, stream);  // nn keys

    convert_kernel<<<dim3(18, 128), 256, 0, stream>>>(spatial_1, spatial_2, xT, normp);
    cdist_mfma<<<2880, 256, 0, stream>>>(xT, normp, nn1, nn2);
    select_topk_wave<<<dim3(B, 2), 64, 0, stream>>>(nn1, nn2, sel_p, sel_q);
    gather_jmajor<<<dim3(K, 4), 256, 0, stream>>>(xT, sel_p, sel_q, XgT);
    ata_mfma<<<dim3(47, 4, 4), 256, 0, stream>>>(XgT, Mp);
    ata_pooled<<<dim3(12, 12, 2), 256, 0, stream>>>(pooled_1, pooled_2, M, colsum, slots);
    xgt_scan<<<dim3(192, 2), 256, 0, stream>>>(XgT, colsum, slots);
    cov_kernel<<<dim3(48, 6), 256, 0, stream>>>(Mp, M, colsum, slots);
    final_kernel<<<1, 1, 0, stream>>>(slots, out);
}